// Round 1
// baseline (1212.242 us; speedup 1.0000x reference)
//
#include <hip/hip_runtime.h>
#include <hip/hip_bf16.h>
#include <math.h>

// Problem constants (match reference)
#define NNODES 100000
#define IN_DIM 128
#define HID 128
#define HEADS 2
#define F2 256              // HEADS*HID
#define NEDGES 800000
#define ETOT 900000         // NEDGES + NNODES self-loops
#define NEG_SLOPE 0.2f

// ---------------------------------------------------------------------------
// CSR build: histogram -> scan -> scatter
// ---------------------------------------------------------------------------
__global__ __launch_bounds__(256) void hist_kernel(const int* __restrict__ ei,
                                                   int* __restrict__ deg) {
    int i = blockIdx.x * 256 + threadIdx.x;
    if (i >= ETOT) return;
    int dst = (i < NEDGES) ? ei[NEDGES + i] : (i - NEDGES);
    atomicAdd(&deg[dst], 1);
}

// per-256-block exclusive scan; writes block totals
__global__ __launch_bounds__(256) void scan1_kernel(const int* __restrict__ deg,
                                                    int* __restrict__ row_start,
                                                    int* __restrict__ bsum) {
    __shared__ int s[256];
    int t = threadIdx.x;
    int i = blockIdx.x * 256 + t;
    int v = (i < NNODES) ? deg[i] : 0;
    s[t] = v;
    __syncthreads();
    for (int off = 1; off < 256; off <<= 1) {
        int x = (t >= off) ? s[t - off] : 0;
        __syncthreads();
        s[t] += x;
        __syncthreads();
    }
    if (i < NNODES) row_start[i] = s[t] - v;   // exclusive
    if (t == 255) bsum[blockIdx.x] = s[255];
}

// scan of block sums (<=512 entries), exclusive
__global__ __launch_bounds__(512) void scan2_kernel(const int* __restrict__ bsum,
                                                    int* __restrict__ bsum2,
                                                    int cnt) {
    __shared__ int s[512];
    int t = threadIdx.x;
    int v = (t < cnt) ? bsum[t] : 0;
    s[t] = v;
    __syncthreads();
    for (int off = 1; off < 512; off <<= 1) {
        int x = (t >= off) ? s[t - off] : 0;
        __syncthreads();
        s[t] += x;
        __syncthreads();
    }
    bsum2[t] = s[t] - v;   // exclusive
}

__global__ __launch_bounds__(256) void scan3_kernel(int* __restrict__ row_start,
                                                    const int* __restrict__ bsum2,
                                                    int* __restrict__ cursor) {
    int i = blockIdx.x * 256 + threadIdx.x;
    if (i == 0) row_start[NNODES] = ETOT;
    if (i >= NNODES) return;
    int r = row_start[i] + bsum2[i >> 8];
    row_start[i] = r;
    cursor[i] = r;
}

__global__ __launch_bounds__(256) void scatter_kernel(const int* __restrict__ ei,
                                                      int* __restrict__ cursor,
                                                      int* __restrict__ csr_src) {
    int i = blockIdx.x * 256 + threadIdx.x;
    if (i >= ETOT) return;
    int src, dst;
    if (i < NEDGES) { src = ei[i]; dst = ei[NEDGES + i]; }
    else            { src = i - NEDGES; dst = src; }
    int pos = atomicAdd(&cursor[dst], 1);
    csr_src[pos] = src;
}

// ---------------------------------------------------------------------------
// fp32 tiled GEMM: C[M x N] = A[M x K] @ B[K x N]  (+ optional bias)
// BM=BN=64, BK=16, 256 threads, 4x4 per thread
// ---------------------------------------------------------------------------
__global__ __launch_bounds__(256) void gemm_kernel(const float* __restrict__ A,
                                                   const float* __restrict__ B,
                                                   float* __restrict__ C,
                                                   const float* __restrict__ bias,
                                                   int M, int N, int K, int fuse_bias) {
    __shared__ float As[16][65];   // [k][m], padded
    __shared__ float Bs[16][64];   // [k][n]
    int t = threadIdx.x;
    int tn = t & 15;
    int tm = t >> 4;
    int rowBase = blockIdx.x * 64;
    int colBase = blockIdx.y * 64;
    float acc[4][4] = {};

    for (int k0 = 0; k0 < K; k0 += 16) {
        {   // A tile: 64 rows x 16 cols, one float4 per thread
            int arow = t >> 2;
            int acol = (t & 3) * 4;
            float4 av = make_float4(0.f, 0.f, 0.f, 0.f);
            int gr = rowBase + arow;
            if (gr < M)
                av = *reinterpret_cast<const float4*>(&A[(size_t)gr * K + k0 + acol]);
            As[acol + 0][arow] = av.x;
            As[acol + 1][arow] = av.y;
            As[acol + 2][arow] = av.z;
            As[acol + 3][arow] = av.w;
        }
        {   // B tile: 16 rows x 64 cols, one float4 per thread
            int brow = t >> 4;
            int bcol = (t & 15) * 4;
            float4 bv = *reinterpret_cast<const float4*>(&B[(size_t)(k0 + brow) * N + colBase + bcol]);
            *reinterpret_cast<float4*>(&Bs[brow][bcol]) = bv;
        }
        __syncthreads();
#pragma unroll
        for (int kk = 0; kk < 16; kk++) {
            float a[4], b[4];
#pragma unroll
            for (int i = 0; i < 4; i++) a[i] = As[kk][tm * 4 + i];
#pragma unroll
            for (int j = 0; j < 4; j++) b[j] = Bs[kk][tn * 4 + j];
#pragma unroll
            for (int i = 0; i < 4; i++)
#pragma unroll
                for (int j = 0; j < 4; j++) acc[i][j] += a[i] * b[j];
        }
        __syncthreads();
    }
#pragma unroll
    for (int i = 0; i < 4; i++) {
        int gr = rowBase + tm * 4 + i;
        if (gr >= M) break;
#pragma unroll
        for (int j = 0; j < 4; j++) {
            int gc = colBase + tn * 4 + j;
            float v = acc[i][j];
            if (fuse_bias) v += bias[gc];
            C[(size_t)gr * N + gc] = v;
        }
    }
}

// ---------------------------------------------------------------------------
// per-node attention logits: as[n,h] = dot(h[n,h,:], a_src[h,:]); same for ad
// ---------------------------------------------------------------------------
__global__ __launch_bounds__(256) void alpha_kernel(const float* __restrict__ h,
                                                    const float* __restrict__ a_src,
                                                    const float* __restrict__ a_dst,
                                                    float* __restrict__ as_,
                                                    float* __restrict__ ad_) {
    int n = blockIdx.x;
    int t = threadIdx.x;
    int head = t >> 7;
    float hv = h[(size_t)n * F2 + t];
    __shared__ float r0[256], r1[256];
    r0[t] = hv * a_src[t];
    r1[t] = hv * a_dst[t];
    __syncthreads();
    int l = t & 127;
    for (int sft = 64; sft > 0; sft >>= 1) {
        if (l < sft) { r0[t] += r0[t + sft]; r1[t] += r1[t + sft]; }
        __syncthreads();
    }
    if (l == 0) {
        as_[2 * n + head] = r0[t];
        ad_[2 * n + head] = r1[t];
    }
}

// ---------------------------------------------------------------------------
// per-dst-node segment softmax + weighted aggregation (no atomics)
// out[n, f] = relu( sum_e w_e * h[src_e, f] / denom + bias[f] )
// ---------------------------------------------------------------------------
__global__ __launch_bounds__(256) void agg_kernel(const float* __restrict__ h,
                                                  const float* __restrict__ as_,
                                                  const float* __restrict__ ad_,
                                                  const int* __restrict__ row_start,
                                                  const int* __restrict__ csr_src,
                                                  const float* __restrict__ bias,
                                                  float* __restrict__ out,
                                                  int do_relu) {
    int n = blockIdx.x;
    int t = threadIdx.x;
    int head = t >> 7;
    int beg = row_start[n];
    int end = row_start[n + 1];
    float ad0 = ad_[2 * n], ad1 = ad_[2 * n + 1];

    // phase 1: per-head max logit over incoming edges
    float m0 = -1e30f, m1 = -1e30f;
    for (int i = beg + t; i < end; i += 256) {
        int s = csr_src[i];
        float l0 = as_[2 * s] + ad0;     l0 = l0 > 0.f ? l0 : NEG_SLOPE * l0;
        float l1 = as_[2 * s + 1] + ad1; l1 = l1 > 0.f ? l1 : NEG_SLOPE * l1;
        m0 = fmaxf(m0, l0);
        m1 = fmaxf(m1, l1);
    }
    __shared__ float r0[256], r1[256];
    r0[t] = m0; r1[t] = m1;
    __syncthreads();
    for (int sft = 128; sft > 0; sft >>= 1) {
        if (t < sft) { r0[t] = fmaxf(r0[t], r0[t + sft]); r1[t] = fmaxf(r1[t], r1[t + sft]); }
        __syncthreads();
    }
    float gm0 = r0[0], gm1 = r1[0];
    __syncthreads();

    // phase 2: chunked exp-weight + weighted feature accumulation
    __shared__ int   s_src[64];
    __shared__ float s_w[2][64];
    float acc = 0.f;
    float dsum0 = 0.f, dsum1 = 0.f;
    for (int chunk = beg; chunk < end; chunk += 64) {
        int cnt = min(64, end - chunk);
        if (t < cnt) {
            int s = csr_src[chunk + t];
            float l0 = as_[2 * s] + ad0;     l0 = l0 > 0.f ? l0 : NEG_SLOPE * l0;
            float l1 = as_[2 * s + 1] + ad1; l1 = l1 > 0.f ? l1 : NEG_SLOPE * l1;
            float w0 = expf(l0 - gm0);
            float w1 = expf(l1 - gm1);
            s_src[t] = s;
            s_w[0][t] = w0;
            s_w[1][t] = w1;
            dsum0 += w0;
            dsum1 += w1;
        }
        __syncthreads();
        for (int j = 0; j < cnt; j++) {
            int s = s_src[j];
            float w = s_w[head][j];
            acc += h[(size_t)s * F2 + t] * w;     // coalesced 1KB per edge
        }
        __syncthreads();
    }
    // reduce denominators
    r0[t] = dsum0; r1[t] = dsum1;
    __syncthreads();
    for (int sft = 128; sft > 0; sft >>= 1) {
        if (t < sft) { r0[t] += r0[t + sft]; r1[t] += r1[t + sft]; }
        __syncthreads();
    }
    float denom = (head ? r1[0] : r0[0]) + 1e-16f;
    float v = acc / denom + bias[t];
    if (do_relu) v = fmaxf(v, 0.f);
    out[(size_t)n * F2 + t] = v;
}

// ---------------------------------------------------------------------------
// final: out = sigmoid(h3 @ Wp2 + bp2), h3: [N,128], Wp2: [128,2]
// one wave per node
// ---------------------------------------------------------------------------
__global__ __launch_bounds__(256) void post2_kernel(const float* __restrict__ h3,
                                                    const float* __restrict__ Wp2,
                                                    const float* __restrict__ bp2,
                                                    float* __restrict__ out) {
    int wave = threadIdx.x >> 6;
    int lane = threadIdx.x & 63;
    int n = blockIdx.x * 4 + wave;
    if (n >= NNODES) return;
    float h0 = h3[(size_t)n * 128 + lane];
    float h1 = h3[(size_t)n * 128 + 64 + lane];
    float p0 = h0 * Wp2[lane * 2]     + h1 * Wp2[(64 + lane) * 2];
    float p1 = h0 * Wp2[lane * 2 + 1] + h1 * Wp2[(64 + lane) * 2 + 1];
    for (int off = 32; off > 0; off >>= 1) {
        p0 += __shfl_down(p0, off);
        p1 += __shfl_down(p1, off);
    }
    if (lane == 0) {
        out[2 * n]     = 1.f / (1.f + expf(-(p0 + bp2[0])));
        out[2 * n + 1] = 1.f / (1.f + expf(-(p1 + bp2[1])));
    }
}

// ---------------------------------------------------------------------------
extern "C" void kernel_launch(void* const* d_in, const int* in_sizes, int n_in,
                              void* d_out, int out_size, void* d_ws, size_t ws_size,
                              hipStream_t stream) {
    const float* x      = (const float*)d_in[0];
    const int*   ei     = (const int*)d_in[1];
    const float* W1     = (const float*)d_in[2];
    const float* a_src1 = (const float*)d_in[3];
    const float* a_dst1 = (const float*)d_in[4];
    const float* b1     = (const float*)d_in[5];
    const float* W2     = (const float*)d_in[6];
    const float* a_src2 = (const float*)d_in[7];
    const float* a_dst2 = (const float*)d_in[8];
    const float* b2     = (const float*)d_in[9];
    const float* Wp1    = (const float*)d_in[10];
    const float* bp1    = (const float*)d_in[11];
    const float* Wp2    = (const float*)d_in[12];
    const float* bp2    = (const float*)d_in[13];
    float* outp = (float*)d_out;

    // workspace carve-up
    char* w = (char*)d_ws;
    float* h    = (float*)w;  w += (size_t)NNODES * F2 * sizeof(float);   // 102.4 MB
    float* outb = (float*)w;  w += (size_t)NNODES * F2 * sizeof(float);   // 102.4 MB
    float* as_  = (float*)w;  w += (size_t)NNODES * 2 * sizeof(float);
    float* ad_  = (float*)w;  w += (size_t)NNODES * 2 * sizeof(float);
    int* deg       = (int*)w; w += (size_t)NNODES * sizeof(int);
    int* row_start = (int*)w; w += (size_t)(NNODES + 1) * sizeof(int);
    int* cursor    = (int*)w; w += (size_t)NNODES * sizeof(int);
    int* csr_src   = (int*)w; w += (size_t)ETOT * sizeof(int);
    int* bsum      = (int*)w; w += 512 * sizeof(int);
    int* bsum2     = (int*)w; w += 512 * sizeof(int);

    const int SCAN_BLOCKS = (NNODES + 255) / 256;   // 391

    // --- CSR build ---
    hipMemsetAsync(deg, 0, (size_t)NNODES * sizeof(int), stream);
    hist_kernel<<<(ETOT + 255) / 256, 256, 0, stream>>>(ei, deg);
    scan1_kernel<<<SCAN_BLOCKS, 256, 0, stream>>>(deg, row_start, bsum);
    scan2_kernel<<<1, 512, 0, stream>>>(bsum, bsum2, SCAN_BLOCKS);
    scan3_kernel<<<SCAN_BLOCKS, 256, 0, stream>>>(row_start, bsum2, cursor);
    scatter_kernel<<<(ETOT + 255) / 256, 256, 0, stream>>>(ei, cursor, csr_src);

    dim3 gemm_block(256);
    const int MB = (NNODES + 63) / 64;   // 1563

    // --- layer 1 ---
    gemm_kernel<<<dim3(MB, F2 / 64), gemm_block, 0, stream>>>(x, W1, h, nullptr,
                                                              NNODES, F2, IN_DIM, 0);
    alpha_kernel<<<NNODES, 256, 0, stream>>>(h, a_src1, a_dst1, as_, ad_);
    agg_kernel<<<NNODES, 256, 0, stream>>>(h, as_, ad_, row_start, csr_src, b1, outb, 1);

    // --- layer 2 ---
    gemm_kernel<<<dim3(MB, F2 / 64), gemm_block, 0, stream>>>(outb, W2, h, nullptr,
                                                              NNODES, F2, F2, 0);
    alpha_kernel<<<NNODES, 256, 0, stream>>>(h, a_src2, a_dst2, as_, ad_);
    agg_kernel<<<NNODES, 256, 0, stream>>>(h, as_, ad_, row_start, csr_src, b2, outb, 1);

    // --- post_mp ---
    gemm_kernel<<<dim3(MB, 128 / 64), gemm_block, 0, stream>>>(outb, Wp1, h, bp1,
                                                               NNODES, 128, F2, 1);
    post2_kernel<<<(NNODES + 3) / 4, 256, 0, stream>>>(h, Wp2, bp2, outp);
}

// Round 2
// 846.162 us; speedup vs baseline: 1.4326x; 1.4326x over previous
//
#include <hip/hip_runtime.h>
#include <hip/hip_bf16.h>
#include <math.h>

// Problem constants (match reference)
#define NNODES 100000
#define NPAD   100032        // padded to multiple of 64 for guard-free GEMM
#define IN_DIM 128
#define HID 128
#define HEADS 2
#define F2 256               // HEADS*HID
#define NEDGES 800000
#define ETOT 900000          // NEDGES + NNODES self-loops
#define NEG_SLOPE 0.2f

typedef unsigned int uint;
typedef unsigned short ushort;
typedef __attribute__((ext_vector_type(8))) short short8;
typedef __attribute__((ext_vector_type(4))) float floatx4;

__device__ __forceinline__ ushort f2bf(float f) {
    uint u = __builtin_bit_cast(uint, f);
    u += 0x7fffu + ((u >> 16) & 1u);       // round-to-nearest-even
    return (ushort)(u >> 16);
}
__device__ __forceinline__ float bf2f(uint u16) {
    return __builtin_bit_cast(float, u16 << 16);
}
__device__ __forceinline__ float wred_sum(float v) {
    for (int o = 32; o; o >>= 1) v += __shfl_xor(v, o);
    return v;
}
__device__ __forceinline__ float wred_max(float v) {
    for (int o = 32; o; o >>= 1) v = fmaxf(v, __shfl_xor(v, o));
    return v;
}

// ---------------------------------------------------------------------------
// CSR build: histogram -> scan -> scatter
// ---------------------------------------------------------------------------
__global__ __launch_bounds__(256) void hist_kernel(const int* __restrict__ ei,
                                                   int* __restrict__ deg) {
    int i = blockIdx.x * 256 + threadIdx.x;
    if (i >= ETOT) return;
    int dst = (i < NEDGES) ? ei[NEDGES + i] : (i - NEDGES);
    atomicAdd(&deg[dst], 1);
}

__global__ __launch_bounds__(256) void scan1_kernel(const int* __restrict__ deg,
                                                    int* __restrict__ row_start,
                                                    int* __restrict__ bsum) {
    __shared__ int s[256];
    int t = threadIdx.x;
    int i = blockIdx.x * 256 + t;
    int v = (i < NNODES) ? deg[i] : 0;
    s[t] = v;
    __syncthreads();
    for (int off = 1; off < 256; off <<= 1) {
        int x = (t >= off) ? s[t - off] : 0;
        __syncthreads();
        s[t] += x;
        __syncthreads();
    }
    if (i < NNODES) row_start[i] = s[t] - v;   // exclusive
    if (t == 255) bsum[blockIdx.x] = s[255];
}

__global__ __launch_bounds__(512) void scan2_kernel(const int* __restrict__ bsum,
                                                    int* __restrict__ bsum2,
                                                    int cnt) {
    __shared__ int s[512];
    int t = threadIdx.x;
    int v = (t < cnt) ? bsum[t] : 0;
    s[t] = v;
    __syncthreads();
    for (int off = 1; off < 512; off <<= 1) {
        int x = (t >= off) ? s[t - off] : 0;
        __syncthreads();
        s[t] += x;
        __syncthreads();
    }
    bsum2[t] = s[t] - v;   // exclusive
}

__global__ __launch_bounds__(256) void scan3_kernel(int* __restrict__ row_start,
                                                    const int* __restrict__ bsum2,
                                                    int* __restrict__ cursor) {
    int i = blockIdx.x * 256 + threadIdx.x;
    if (i == 0) row_start[NNODES] = ETOT;
    if (i >= NNODES) return;
    int r = row_start[i] + bsum2[i >> 8];
    row_start[i] = r;
    cursor[i] = r;
}

__global__ __launch_bounds__(256) void scatter_kernel(const int* __restrict__ ei,
                                                      int* __restrict__ cursor,
                                                      int* __restrict__ csr_src) {
    int i = blockIdx.x * 256 + threadIdx.x;
    if (i >= ETOT) return;
    int src, dst;
    if (i < NEDGES) { src = ei[i]; dst = ei[NEDGES + i]; }
    else            { src = i - NEDGES; dst = src; }
    int pos = atomicAdd(&cursor[dst], 1);
    csr_src[pos] = src;
}

// ---------------------------------------------------------------------------
// fp32 -> bf16 elementwise convert
// ---------------------------------------------------------------------------
__global__ __launch_bounds__(256) void convert_kernel(const float* __restrict__ in,
                                                      ushort* __restrict__ out, int n) {
    int i = blockIdx.x * 256 + threadIdx.x;
    if (i < n) out[i] = f2bf(in[i]);
}

// W[K][N] fp32 -> Wt[N][K] bf16   (weights are tiny; naive is fine)
__global__ __launch_bounds__(256) void transpose_bf_kernel(const float* __restrict__ W,
                                                           ushort* __restrict__ Wt,
                                                           int K, int N) {
    int i = blockIdx.x * 256 + threadIdx.x;
    if (i >= K * N) return;
    int n = i / K, k = i - n * K;          // K is 128 or 256 -> shifts
    Wt[(size_t)n * K + k] = f2bf(W[(size_t)k * N + n]);
}

// ---------------------------------------------------------------------------
// bf16 MFMA GEMM: C[Mpad x N] = A[Mpad x K] @ Bt[N x K]^T  (+ optional fp32 bias)
// block tile 64x64, 4 waves (each wave: 16 rows x 64 cols), BK=32
// LDS row stride 40 ushorts (80B = 20 banks) -> 2-way (free) b64 frag reads
// ---------------------------------------------------------------------------
__global__ __launch_bounds__(256) void mfma_gemm(const ushort* __restrict__ A,
                                                 const ushort* __restrict__ Bt,
                                                 ushort* __restrict__ C,
                                                 const float* __restrict__ bias,
                                                 int N, int K, int fuse_bias) {
    __shared__ ushort As[64][40];
    __shared__ ushort Bs[64][40];
    int t = threadIdx.x;
    int wave = t >> 6, lane = t & 63;
    int quad = lane >> 4, l16 = lane & 15;
    size_t rowBase = (size_t)blockIdx.x * 64;
    int colBase = blockIdx.y * 64;

    floatx4 acc[4];
#pragma unroll
    for (int i = 0; i < 4; i++) acc[i] = (floatx4){0.f, 0.f, 0.f, 0.f};

    // staging assignment: thread t loads 8 bf16 at (row = t>>2, kcol = (t&3)*8)
    int ar = t >> 2, ac = (t & 3) * 8;
    const ushort* Ap = A + (rowBase + ar) * K + ac;
    const ushort* Bp = Bt + (size_t)(colBase + ar) * K + ac;

    for (int k0 = 0; k0 < K; k0 += 32) {
        uint4 av = *reinterpret_cast<const uint4*>(Ap + k0);
        uint4 bv = *reinterpret_cast<const uint4*>(Bp + k0);
        *reinterpret_cast<uint2*>(&As[ar][ac])     = make_uint2(av.x, av.y);
        *reinterpret_cast<uint2*>(&As[ar][ac + 4]) = make_uint2(av.z, av.w);
        *reinterpret_cast<uint2*>(&Bs[ar][ac])     = make_uint2(bv.x, bv.y);
        *reinterpret_cast<uint2*>(&Bs[ar][ac + 4]) = make_uint2(bv.z, bv.w);
        __syncthreads();

        union { uint2 u[2]; short8 s; } afr, bfr;
        afr.u[0] = *reinterpret_cast<const uint2*>(&As[wave * 16 + l16][quad * 8]);
        afr.u[1] = *reinterpret_cast<const uint2*>(&As[wave * 16 + l16][quad * 8 + 4]);
#pragma unroll
        for (int nt = 0; nt < 4; nt++) {
            bfr.u[0] = *reinterpret_cast<const uint2*>(&Bs[nt * 16 + l16][quad * 8]);
            bfr.u[1] = *reinterpret_cast<const uint2*>(&Bs[nt * 16 + l16][quad * 8 + 4]);
            acc[nt] = __builtin_amdgcn_mfma_f32_16x16x32_bf16(afr.s, bfr.s, acc[nt], 0, 0, 0);
        }
        __syncthreads();
    }

    // epilogue: D row = quad*4+reg, col = l16 (within each 16x16 tile)
#pragma unroll
    for (int nt = 0; nt < 4; nt++) {
        int col = colBase + nt * 16 + l16;
        float badd = fuse_bias ? bias[col] : 0.f;
#pragma unroll
        for (int r = 0; r < 4; r++) {
            size_t row = rowBase + wave * 16 + quad * 4 + r;
            C[row * N + col] = f2bf(acc[nt][r] + badd);
        }
    }
}

// ---------------------------------------------------------------------------
// per-node attention logits from bf16 h (pairs): wave per node
// as_[n] = (dot(h[n,0,:],a_src[0,:]), dot(h[n,1,:],a_src[1,:])); same for ad_
// ---------------------------------------------------------------------------
__global__ __launch_bounds__(256) void alpha_kernel(const uint* __restrict__ hb2,
                                                    const float* __restrict__ a_src,
                                                    const float* __restrict__ a_dst,
                                                    float2* __restrict__ as_,
                                                    float2* __restrict__ ad_) {
    int wave = threadIdx.x >> 6, lane = threadIdx.x & 63;
    int n = blockIdx.x * 4 + wave;
    if (n >= NNODES) return;
    uint p0 = hb2[(size_t)n * 128 + lane];        // features 2l, 2l+1   (head 0)
    uint p1 = hb2[(size_t)n * 128 + 64 + lane];   // features 128+2l,... (head 1)
    float h00 = bf2f(p0 & 0xffffu), h01 = bf2f(p0 >> 16);
    float h10 = bf2f(p1 & 0xffffu), h11 = bf2f(p1 >> 16);
    float2 s0 = reinterpret_cast<const float2*>(a_src)[lane];
    float2 s1 = reinterpret_cast<const float2*>(a_src)[64 + lane];
    float2 d0 = reinterpret_cast<const float2*>(a_dst)[lane];
    float2 d1 = reinterpret_cast<const float2*>(a_dst)[64 + lane];
    float as0 = wred_sum(h00 * s0.x + h01 * s0.y);
    float as1 = wred_sum(h10 * s1.x + h11 * s1.y);
    float ad0 = wred_sum(h00 * d0.x + h01 * d0.y);
    float ad1 = wred_sum(h10 * d1.x + h11 * d1.y);
    if (lane == 0) {
        as_[n] = make_float2(as0, as1);
        ad_[n] = make_float2(ad0, ad1);
    }
}

// ---------------------------------------------------------------------------
// per-edge softmax weights + per-node inverse denominator: wave per node
// ---------------------------------------------------------------------------
__global__ __launch_bounds__(256) void weights_kernel(const float2* __restrict__ as_,
                                                      const float2* __restrict__ ad_,
                                                      const int* __restrict__ row_start,
                                                      const int* __restrict__ csr_src,
                                                      float2* __restrict__ ew,
                                                      float2* __restrict__ invden) {
    int wave = threadIdx.x >> 6, lane = threadIdx.x & 63;
    int n = blockIdx.x * 4 + wave;
    if (n >= NNODES) return;
    int beg = row_start[n], end = row_start[n + 1];
    float2 ad = ad_[n];
    float m0 = -1e30f, m1 = -1e30f;
    for (int i = beg + lane; i < end; i += 64) {
        float2 as = as_[csr_src[i]];
        float l0 = as.x + ad.x; l0 = l0 > 0.f ? l0 : NEG_SLOPE * l0;
        float l1 = as.y + ad.y; l1 = l1 > 0.f ? l1 : NEG_SLOPE * l1;
        m0 = fmaxf(m0, l0);
        m1 = fmaxf(m1, l1);
    }
    m0 = wred_max(m0);
    m1 = wred_max(m1);
    float s0 = 0.f, s1 = 0.f;
    for (int i = beg + lane; i < end; i += 64) {
        float2 as = as_[csr_src[i]];
        float l0 = as.x + ad.x; l0 = l0 > 0.f ? l0 : NEG_SLOPE * l0;
        float l1 = as.y + ad.y; l1 = l1 > 0.f ? l1 : NEG_SLOPE * l1;
        float w0 = expf(l0 - m0);
        float w1 = expf(l1 - m1);
        ew[i] = make_float2(w0, w1);
        s0 += w0;
        s1 += w1;
    }
    s0 = wred_sum(s0);
    s1 = wred_sum(s1);
    if (lane == 0)
        invden[n] = make_float2(1.f / (s0 + 1e-16f), 1.f / (s1 + 1e-16f));
}

// ---------------------------------------------------------------------------
// pure weighted gather: block per node, 2 edges x 128 bf16-pairs per iter
// out[n,:] = maybe_relu( (sum_e w_e * h[src_e,:]) * invden + bias )
// ---------------------------------------------------------------------------
__global__ __launch_bounds__(256) void gather_kernel(const uint* __restrict__ hb2,
                                                     const int* __restrict__ row_start,
                                                     const int* __restrict__ csr_src,
                                                     const float2* __restrict__ ew,
                                                     const float2* __restrict__ invden,
                                                     const float* __restrict__ bias,
                                                     uint* __restrict__ outb2,
                                                     int do_relu) {
    int n = blockIdx.x;
    int t = threadIdx.x;
    int fp = t & 127;        // feature pair 0..127
    int ep = t >> 7;         // edge parity
    int head = fp >> 6;      // wave-uniform
    int beg = row_start[n], end = row_start[n + 1];
    float a0 = 0.f, a1 = 0.f;
    for (int j = beg + ep; j < end; j += 2) {
        int s = csr_src[j];                 // wave-uniform -> broadcast
        float2 wv = ew[j];
        float w = head ? wv.y : wv.x;
        uint hv = hb2[(size_t)s * 128 + fp];   // coalesced 256B per wave
        a0 += w * bf2f(hv & 0xffffu);
        a1 += w * bf2f(hv >> 16);
    }
    __shared__ float sa[256], sb[256];
    sa[t] = a0; sb[t] = a1;
    __syncthreads();
    if (t < 128) {
        float v0 = sa[t] + sa[t + 128];
        float v1 = sb[t] + sb[t + 128];
        float2 inv = invden[n];
        float iv = (t >> 6) ? inv.y : inv.x;
        float2 b = reinterpret_cast<const float2*>(bias)[t];
        float o0 = v0 * iv + b.x;
        float o1 = v1 * iv + b.y;
        if (do_relu) { o0 = fmaxf(o0, 0.f); o1 = fmaxf(o1, 0.f); }
        outb2[(size_t)n * 128 + t] = (uint)f2bf(o0) | ((uint)f2bf(o1) << 16);
    }
}

// ---------------------------------------------------------------------------
// final: out = sigmoid(h3 @ Wp2 + bp2), h3 bf16 [N,128], Wp2 fp32 [128,2]
// ---------------------------------------------------------------------------
__global__ __launch_bounds__(256) void post2_kernel(const uint* __restrict__ h3,
                                                    const float* __restrict__ Wp2,
                                                    const float* __restrict__ bp2,
                                                    float* __restrict__ out) {
    int wave = threadIdx.x >> 6, lane = threadIdx.x & 63;
    int n = blockIdx.x * 4 + wave;
    if (n >= NNODES) return;
    uint p = h3[(size_t)n * 64 + lane];
    float ha = bf2f(p & 0xffffu), hb = bf2f(p >> 16);
    float4 w = *reinterpret_cast<const float4*>(&Wp2[lane * 4]);
    float p0 = wred_sum(ha * w.x + hb * w.z);
    float p1 = wred_sum(ha * w.y + hb * w.w);
    if (lane == 0) {
        out[2 * n]     = 1.f / (1.f + expf(-(p0 + bp2[0])));
        out[2 * n + 1] = 1.f / (1.f + expf(-(p1 + bp2[1])));
    }
}

// ---------------------------------------------------------------------------
extern "C" void kernel_launch(void* const* d_in, const int* in_sizes, int n_in,
                              void* d_out, int out_size, void* d_ws, size_t ws_size,
                              hipStream_t stream) {
    const float* x      = (const float*)d_in[0];
    const int*   ei     = (const int*)d_in[1];
    const float* W1     = (const float*)d_in[2];
    const float* a_src1 = (const float*)d_in[3];
    const float* a_dst1 = (const float*)d_in[4];
    const float* b1     = (const float*)d_in[5];
    const float* W2     = (const float*)d_in[6];
    const float* a_src2 = (const float*)d_in[7];
    const float* a_dst2 = (const float*)d_in[8];
    const float* b2     = (const float*)d_in[9];
    const float* Wp1    = (const float*)d_in[10];
    const float* bp1    = (const float*)d_in[11];
    const float* Wp2    = (const float*)d_in[12];
    const float* bp2    = (const float*)d_in[13];
    float* outp = (float*)d_out;

    // workspace carve-up (all regions 16B aligned)
    char* w = (char*)d_ws;
    ushort* xbf  = (ushort*)w; w += (size_t)NPAD * 128 * sizeof(ushort);  // 25.6MB, reused as h3
    ushort* hbf  = (ushort*)w; w += (size_t)NPAD * 256 * sizeof(ushort);  // 51.2MB
    ushort* obf  = (ushort*)w; w += (size_t)NPAD * 256 * sizeof(ushort);  // 51.2MB
    ushort* W1t  = (ushort*)w; w += (size_t)256 * 128 * sizeof(ushort);
    ushort* W2t  = (ushort*)w; w += (size_t)256 * 256 * sizeof(ushort);
    ushort* Wp1t = (ushort*)w; w += (size_t)128 * 256 * sizeof(ushort);
    float2* as_  = (float2*)w; w += (size_t)NNODES * sizeof(float2);
    float2* ad_  = (float2*)w; w += (size_t)NNODES * sizeof(float2);
    float2* ew   = (float2*)w; w += (size_t)ETOT * sizeof(float2);        // 7.2MB
    float2* invd = (float2*)w; w += (size_t)NNODES * sizeof(float2);
    int* deg       = (int*)w; w += (size_t)NNODES * sizeof(int);
    int* row_start = (int*)w; w += (size_t)(NNODES + 16) * sizeof(int);
    int* cursor    = (int*)w; w += (size_t)NNODES * sizeof(int);
    int* csr_src   = (int*)w; w += (size_t)ETOT * sizeof(int);
    int* bsum      = (int*)w; w += 512 * sizeof(int);
    int* bsum2     = (int*)w; w += 512 * sizeof(int);

    const int SCAN_BLOCKS = (NNODES + 255) / 256;   // 391
    const int NODE_WAVES  = (NNODES + 3) / 4;       // 25000 blocks of 4 waves

    // --- CSR build ---
    hipMemsetAsync(deg, 0, (size_t)NNODES * sizeof(int), stream);
    hist_kernel<<<(ETOT + 255) / 256, 256, 0, stream>>>(ei, deg);
    scan1_kernel<<<SCAN_BLOCKS, 256, 0, stream>>>(deg, row_start, bsum);
    scan2_kernel<<<1, 512, 0, stream>>>(bsum, bsum2, SCAN_BLOCKS);
    scan3_kernel<<<SCAN_BLOCKS, 256, 0, stream>>>(row_start, bsum2, cursor);
    scatter_kernel<<<(ETOT + 255) / 256, 256, 0, stream>>>(ei, cursor, csr_src);

    // --- bf16 conversions ---
    convert_kernel<<<(NNODES * 128 + 255) / 256, 256, 0, stream>>>(x, xbf, NNODES * 128);
    transpose_bf_kernel<<<(128 * 256 + 255) / 256, 256, 0, stream>>>(W1, W1t, 128, 256);
    transpose_bf_kernel<<<(256 * 256 + 255) / 256, 256, 0, stream>>>(W2, W2t, 256, 256);
    transpose_bf_kernel<<<(256 * 128 + 255) / 256, 256, 0, stream>>>(Wp1, Wp1t, 256, 128);

    const int MB = NPAD / 64;   // 1563

    // --- layer 1 ---
    mfma_gemm<<<dim3(MB, 4), 256, 0, stream>>>(xbf, W1t, hbf, nullptr, 256, 128, 0);
    alpha_kernel<<<NODE_WAVES, 256, 0, stream>>>((const uint*)hbf, a_src1, a_dst1, as_, ad_);
    weights_kernel<<<NODE_WAVES, 256, 0, stream>>>(as_, ad_, row_start, csr_src, ew, invd);
    gather_kernel<<<NNODES, 256, 0, stream>>>((const uint*)hbf, row_start, csr_src, ew, invd,
                                              b1, (uint*)obf, 1);

    // --- layer 2 ---
    mfma_gemm<<<dim3(MB, 4), 256, 0, stream>>>(obf, W2t, hbf, nullptr, 256, 256, 0);
    alpha_kernel<<<NODE_WAVES, 256, 0, stream>>>((const uint*)hbf, a_src2, a_dst2, as_, ad_);
    weights_kernel<<<NODE_WAVES, 256, 0, stream>>>(as_, ad_, row_start, csr_src, ew, invd);
    gather_kernel<<<NNODES, 256, 0, stream>>>((const uint*)hbf, row_start, csr_src, ew, invd,
                                              b2, (uint*)obf, 1);

    // --- post_mp ---
    mfma_gemm<<<dim3(MB, 2), 256, 0, stream>>>(obf, Wp1t, xbf, bp1, 128, 256, 1);
    post2_kernel<<<NODE_WAVES, 256, 0, stream>>>((const uint*)xbf, Wp2, bp2, outp);
}

// Round 3
// 643.355 us; speedup vs baseline: 1.8842x; 1.3152x over previous
//
#include <hip/hip_runtime.h>
#include <hip/hip_bf16.h>
#include <math.h>

// Problem constants (match reference)
#define NNODES 100000
#define NPAD   100032        // padded to multiple of 64 for guard-free GEMM
#define IN_DIM 128
#define HID 128
#define HEADS 2
#define F2 256               // HEADS*HID
#define NEDGES 800000
#define ETOT 900000          // NEDGES + NNODES self-loops
#define NEG_SLOPE 0.2f

typedef unsigned int uint;
typedef unsigned short ushort;
typedef __attribute__((ext_vector_type(8))) short short8;
typedef __attribute__((ext_vector_type(4))) float floatx4;

__device__ __forceinline__ ushort f2bf(float f) {
    uint u = __builtin_bit_cast(uint, f);
    u += 0x7fffu + ((u >> 16) & 1u);       // round-to-nearest-even
    return (ushort)(u >> 16);
}
__device__ __forceinline__ float bf2f(uint u16) {
    return __builtin_bit_cast(float, u16 << 16);
}
__device__ __forceinline__ float wred_sum(float v) {
    for (int o = 32; o; o >>= 1) v += __shfl_xor(v, o);
    return v;
}

// ---------------------------------------------------------------------------
// CSR build: histogram -> scan -> scatter
// ---------------------------------------------------------------------------
__global__ __launch_bounds__(256) void hist_kernel(const int* __restrict__ ei,
                                                   int* __restrict__ deg) {
    int i = blockIdx.x * 256 + threadIdx.x;
    if (i >= ETOT) return;
    int dst = (i < NEDGES) ? ei[NEDGES + i] : (i - NEDGES);
    atomicAdd(&deg[dst], 1);
}

__global__ __launch_bounds__(256) void scan1_kernel(const int* __restrict__ deg,
                                                    int* __restrict__ row_start,
                                                    int* __restrict__ bsum) {
    __shared__ int s[256];
    int t = threadIdx.x;
    int i = blockIdx.x * 256 + t;
    int v = (i < NNODES) ? deg[i] : 0;
    s[t] = v;
    __syncthreads();
    for (int off = 1; off < 256; off <<= 1) {
        int x = (t >= off) ? s[t - off] : 0;
        __syncthreads();
        s[t] += x;
        __syncthreads();
    }
    if (i < NNODES) row_start[i] = s[t] - v;   // exclusive
    if (t == 255) bsum[blockIdx.x] = s[255];
}

__global__ __launch_bounds__(512) void scan2_kernel(const int* __restrict__ bsum,
                                                    int* __restrict__ bsum2,
                                                    int cnt) {
    __shared__ int s[512];
    int t = threadIdx.x;
    int v = (t < cnt) ? bsum[t] : 0;
    s[t] = v;
    __syncthreads();
    for (int off = 1; off < 512; off <<= 1) {
        int x = (t >= off) ? s[t - off] : 0;
        __syncthreads();
        s[t] += x;
        __syncthreads();
    }
    bsum2[t] = s[t] - v;   // exclusive
}

__global__ __launch_bounds__(256) void scan3_kernel(int* __restrict__ row_start,
                                                    const int* __restrict__ bsum2,
                                                    int* __restrict__ cursor) {
    int i = blockIdx.x * 256 + threadIdx.x;
    if (i == 0) row_start[NNODES] = ETOT;
    if (i >= NNODES) return;
    int r = row_start[i] + bsum2[i >> 8];
    row_start[i] = r;
    cursor[i] = r;
}

__global__ __launch_bounds__(256) void scatter_kernel(const int* __restrict__ ei,
                                                      int* __restrict__ cursor,
                                                      int* __restrict__ csr_src) {
    int i = blockIdx.x * 256 + threadIdx.x;
    if (i >= ETOT) return;
    int src, dst;
    if (i < NEDGES) { src = ei[i]; dst = ei[NEDGES + i]; }
    else            { src = i - NEDGES; dst = src; }
    int pos = atomicAdd(&cursor[dst], 1);
    csr_src[pos] = src;
}

// ---------------------------------------------------------------------------
// W[K][N] fp32 -> Wt[N][K] bf16   (weights are tiny; naive is fine)
// ---------------------------------------------------------------------------
__global__ __launch_bounds__(256) void transpose_bf_kernel(const float* __restrict__ W,
                                                           ushort* __restrict__ Wt,
                                                           int K, int N) {
    int i = blockIdx.x * 256 + threadIdx.x;
    if (i >= K * N) return;
    int n = i / K, k = i - n * K;
    Wt[(size_t)n * K + k] = f2bf(W[(size_t)k * N + n]);
}

// Wf[k][0:2] = Wp1[k][:] @ Wp2 ; bf[j] = bp1 @ Wp2[:,j] + bp2[j]   (1 block)
__global__ __launch_bounds__(256) void fw_kernel(const float* __restrict__ Wp1,
                                                 const float* __restrict__ bp1,
                                                 const float* __restrict__ Wp2,
                                                 const float* __restrict__ bp2,
                                                 float2* __restrict__ Wf,
                                                 float* __restrict__ bfv) {
    int k = threadIdx.x;   // 0..255
    float s0 = 0.f, s1 = 0.f;
    for (int m = 0; m < 128; m++) {
        float w = Wp1[(size_t)k * 128 + m];
        s0 += w * Wp2[2 * m];
        s1 += w * Wp2[2 * m + 1];
    }
    Wf[k] = make_float2(s0, s1);
    if (k < 2) {
        float b = bp2[k];
        for (int m = 0; m < 128; m++) b += bp1[m] * Wp2[2 * m + k];
        bfv[k] = b;
    }
}

// ---------------------------------------------------------------------------
// bf16 MFMA GEMM (A fp32, converted in staging): C = A @ Bt^T, fused alpha
// logits (as_[row,head] += sum_c C[row,c]*a_src[c] over this block's cols).
// block tile 64x64, 4 waves (wave: 16 rows x 64 cols), BK=32
// ---------------------------------------------------------------------------
__global__ __launch_bounds__(256) void mfma_gemm_f32A(const float* __restrict__ A,
                                                      const ushort* __restrict__ Bt,
                                                      ushort* __restrict__ C,
                                                      float* __restrict__ as_f,
                                                      float* __restrict__ ad_f,
                                                      const float* __restrict__ aS,
                                                      const float* __restrict__ aD,
                                                      int N, int K) {
    __shared__ ushort As[64][40];
    __shared__ ushort Bs[64][40];
    int t = threadIdx.x;
    int wave = t >> 6, lane = t & 63;
    int quad = lane >> 4, l16 = lane & 15;
    size_t rowBase = (size_t)blockIdx.x * 64;
    int colBase = blockIdx.y * 64;

    floatx4 acc[4];
#pragma unroll
    for (int i = 0; i < 4; i++) acc[i] = (floatx4){0.f, 0.f, 0.f, 0.f};

    int ar = t >> 2, ac = (t & 3) * 8;
    int agr = (int)rowBase + ar;
    const float*  Ap = A + (size_t)agr * K + ac;
    const ushort* Bp = Bt + (size_t)(colBase + ar) * K + ac;
    bool aok = agr < NNODES;

    for (int k0 = 0; k0 < K; k0 += 32) {
        float4 f0 = make_float4(0.f, 0.f, 0.f, 0.f), f1 = f0;
        if (aok) {
            f0 = *reinterpret_cast<const float4*>(Ap + k0);
            f1 = *reinterpret_cast<const float4*>(Ap + k0 + 4);
        }
        uint4 bv = *reinterpret_cast<const uint4*>(Bp + k0);
        uint u0 = (uint)f2bf(f0.x) | ((uint)f2bf(f0.y) << 16);
        uint u1 = (uint)f2bf(f0.z) | ((uint)f2bf(f0.w) << 16);
        uint u2 = (uint)f2bf(f1.x) | ((uint)f2bf(f1.y) << 16);
        uint u3 = (uint)f2bf(f1.z) | ((uint)f2bf(f1.w) << 16);
        *reinterpret_cast<uint2*>(&As[ar][ac])     = make_uint2(u0, u1);
        *reinterpret_cast<uint2*>(&As[ar][ac + 4]) = make_uint2(u2, u3);
        *reinterpret_cast<uint2*>(&Bs[ar][ac])     = make_uint2(bv.x, bv.y);
        *reinterpret_cast<uint2*>(&Bs[ar][ac + 4]) = make_uint2(bv.z, bv.w);
        __syncthreads();

        union { uint2 u[2]; short8 s; } afr, bfr;
        afr.u[0] = *reinterpret_cast<const uint2*>(&As[wave * 16 + l16][quad * 8]);
        afr.u[1] = *reinterpret_cast<const uint2*>(&As[wave * 16 + l16][quad * 8 + 4]);
#pragma unroll
        for (int nt = 0; nt < 4; nt++) {
            bfr.u[0] = *reinterpret_cast<const uint2*>(&Bs[nt * 16 + l16][quad * 8]);
            bfr.u[1] = *reinterpret_cast<const uint2*>(&Bs[nt * 16 + l16][quad * 8 + 4]);
            acc[nt] = __builtin_amdgcn_mfma_f32_16x16x32_bf16(afr.s, bfr.s, acc[nt], 0, 0, 0);
        }
        __syncthreads();
    }

    // C write: D row = quad*4+reg, col = l16 within 16x16 tile
#pragma unroll
    for (int nt = 0; nt < 4; nt++) {
        int col = colBase + nt * 16 + l16;
#pragma unroll
        for (int r = 0; r < 4; r++) {
            size_t row = rowBase + wave * 16 + quad * 4 + r;
            C[row * N + col] = f2bf(acc[nt][r]);
        }
    }
    // fused alpha logits: partial over this block's 64 cols, head uniform
    int head = colBase >> 7;
#pragma unroll
    for (int r = 0; r < 4; r++) {
        float ps = 0.f, pd = 0.f;
#pragma unroll
        for (int nt = 0; nt < 4; nt++) {
            int c = colBase + nt * 16 + l16;
            ps += acc[nt][r] * aS[c];
            pd += acc[nt][r] * aD[c];
        }
#pragma unroll
        for (int o = 1; o < 16; o <<= 1) {
            ps += __shfl_xor(ps, o);
            pd += __shfl_xor(pd, o);
        }
        if (l16 == 0) {
            size_t row = rowBase + wave * 16 + quad * 4 + r;
            atomicAdd(&as_f[2 * row + head], ps);
            atomicAdd(&ad_f[2 * row + head], pd);
        }
    }
}

// same but A already bf16 (padded, no guard)
__global__ __launch_bounds__(256) void mfma_gemm_bf16A(const ushort* __restrict__ A,
                                                       const ushort* __restrict__ Bt,
                                                       ushort* __restrict__ C,
                                                       float* __restrict__ as_f,
                                                       float* __restrict__ ad_f,
                                                       const float* __restrict__ aS,
                                                       const float* __restrict__ aD,
                                                       int N, int K) {
    __shared__ ushort As[64][40];
    __shared__ ushort Bs[64][40];
    int t = threadIdx.x;
    int wave = t >> 6, lane = t & 63;
    int quad = lane >> 4, l16 = lane & 15;
    size_t rowBase = (size_t)blockIdx.x * 64;
    int colBase = blockIdx.y * 64;

    floatx4 acc[4];
#pragma unroll
    for (int i = 0; i < 4; i++) acc[i] = (floatx4){0.f, 0.f, 0.f, 0.f};

    int ar = t >> 2, ac = (t & 3) * 8;
    const ushort* Ap = A + ((size_t)blockIdx.x * 64 + ar) * K + ac;
    const ushort* Bp = Bt + (size_t)(colBase + ar) * K + ac;

    for (int k0 = 0; k0 < K; k0 += 32) {
        uint4 av = *reinterpret_cast<const uint4*>(Ap + k0);
        uint4 bv = *reinterpret_cast<const uint4*>(Bp + k0);
        *reinterpret_cast<uint2*>(&As[ar][ac])     = make_uint2(av.x, av.y);
        *reinterpret_cast<uint2*>(&As[ar][ac + 4]) = make_uint2(av.z, av.w);
        *reinterpret_cast<uint2*>(&Bs[ar][ac])     = make_uint2(bv.x, bv.y);
        *reinterpret_cast<uint2*>(&Bs[ar][ac + 4]) = make_uint2(bv.z, bv.w);
        __syncthreads();

        union { uint2 u[2]; short8 s; } afr, bfr;
        afr.u[0] = *reinterpret_cast<const uint2*>(&As[wave * 16 + l16][quad * 8]);
        afr.u[1] = *reinterpret_cast<const uint2*>(&As[wave * 16 + l16][quad * 8 + 4]);
#pragma unroll
        for (int nt = 0; nt < 4; nt++) {
            bfr.u[0] = *reinterpret_cast<const uint2*>(&Bs[nt * 16 + l16][quad * 8]);
            bfr.u[1] = *reinterpret_cast<const uint2*>(&Bs[nt * 16 + l16][quad * 8 + 4]);
            acc[nt] = __builtin_amdgcn_mfma_f32_16x16x32_bf16(afr.s, bfr.s, acc[nt], 0, 0, 0);
        }
        __syncthreads();
    }

#pragma unroll
    for (int nt = 0; nt < 4; nt++) {
        int col = colBase + nt * 16 + l16;
#pragma unroll
        for (int r = 0; r < 4; r++) {
            size_t row = rowBase + wave * 16 + quad * 4 + r;
            C[row * N + col] = f2bf(acc[nt][r]);
        }
    }
    int head = colBase >> 7;
#pragma unroll
    for (int r = 0; r < 4; r++) {
        float ps = 0.f, pd = 0.f;
#pragma unroll
        for (int nt = 0; nt < 4; nt++) {
            int c = colBase + nt * 16 + l16;
            ps += acc[nt][r] * aS[c];
            pd += acc[nt][r] * aD[c];
        }
#pragma unroll
        for (int o = 1; o < 16; o <<= 1) {
            ps += __shfl_xor(ps, o);
            pd += __shfl_xor(pd, o);
        }
        if (l16 == 0) {
            size_t row = rowBase + wave * 16 + quad * 4 + r;
            atomicAdd(&as_f[2 * row + head], ps);
            atomicAdd(&ad_f[2 * row + head], pd);
        }
    }
}

// ---------------------------------------------------------------------------
// per-edge softmax weights + per-node inverse denominator: thread per node
// ---------------------------------------------------------------------------
__global__ __launch_bounds__(256) void weights_kernel(const float2* __restrict__ as_,
                                                      const float2* __restrict__ ad_,
                                                      const int* __restrict__ row_start,
                                                      const int* __restrict__ csr_src,
                                                      float2* __restrict__ ew,
                                                      float2* __restrict__ invden) {
    int n = blockIdx.x * 256 + threadIdx.x;
    if (n >= NNODES) return;
    int beg = row_start[n], end = row_start[n + 1];
    float2 ad = ad_[n];
    float m0 = -1e30f, m1 = -1e30f;
    for (int i = beg; i < end; i++) {
        float2 as = as_[csr_src[i]];
        float l0 = as.x + ad.x; l0 = l0 > 0.f ? l0 : NEG_SLOPE * l0;
        float l1 = as.y + ad.y; l1 = l1 > 0.f ? l1 : NEG_SLOPE * l1;
        m0 = fmaxf(m0, l0);
        m1 = fmaxf(m1, l1);
    }
    float s0 = 0.f, s1 = 0.f;
    for (int i = beg; i < end; i++) {
        float2 as = as_[csr_src[i]];
        float l0 = as.x + ad.x; l0 = l0 > 0.f ? l0 : NEG_SLOPE * l0;
        float l1 = as.y + ad.y; l1 = l1 > 0.f ? l1 : NEG_SLOPE * l1;
        float w0 = __expf(l0 - m0);
        float w1 = __expf(l1 - m1);
        ew[i] = make_float2(w0, w1);
        s0 += w0;
        s1 += w1;
    }
    invden[n] = make_float2(1.f / (s0 + 1e-16f), 1.f / (s1 + 1e-16f));
}

// ---------------------------------------------------------------------------
// weighted gather, 4 edges in flight per wave:
// out[n,:] = relu( (sum_e w_e * h[src_e,:]) * invden + bias )
// ---------------------------------------------------------------------------
__global__ __launch_bounds__(256) void gather_kernel(const uint* __restrict__ hb2,
                                                     const int* __restrict__ row_start,
                                                     const int* __restrict__ csr_src,
                                                     const float2* __restrict__ ew,
                                                     const float2* __restrict__ invden,
                                                     const float* __restrict__ bias,
                                                     uint* __restrict__ outb2,
                                                     int do_relu) {
    int n = blockIdx.x;
    int t = threadIdx.x;
    int fp = t & 127;        // feature pair 0..127
    int ep = t >> 7;         // edge parity
    int head = fp >> 6;      // wave-uniform
    int beg = row_start[n], end = row_start[n + 1];
    float a0 = 0.f, a1 = 0.f;
    int j = beg + ep;
    for (; j + 6 < end; j += 8) {                 // 4 edges in flight
        int s0 = csr_src[j],     s1 = csr_src[j + 2];
        int s2 = csr_src[j + 4], s3 = csr_src[j + 6];
        float2 w0v = ew[j],     w1v = ew[j + 2];
        float2 w2v = ew[j + 4], w3v = ew[j + 6];
        uint h0 = hb2[(size_t)s0 * 128 + fp];
        uint h1 = hb2[(size_t)s1 * 128 + fp];
        uint h2 = hb2[(size_t)s2 * 128 + fp];
        uint h3 = hb2[(size_t)s3 * 128 + fp];
        float w0 = head ? w0v.y : w0v.x, w1 = head ? w1v.y : w1v.x;
        float w2 = head ? w2v.y : w2v.x, w3 = head ? w3v.y : w3v.x;
        a0 += w0 * bf2f(h0 & 0xffffu) + w1 * bf2f(h1 & 0xffffu)
            + w2 * bf2f(h2 & 0xffffu) + w3 * bf2f(h3 & 0xffffu);
        a1 += w0 * bf2f(h0 >> 16) + w1 * bf2f(h1 >> 16)
            + w2 * bf2f(h2 >> 16) + w3 * bf2f(h3 >> 16);
    }
    for (; j < end; j += 2) {
        int s = csr_src[j];
        float2 wv = ew[j];
        float w = head ? wv.y : wv.x;
        uint hv = hb2[(size_t)s * 128 + fp];
        a0 += w * bf2f(hv & 0xffffu);
        a1 += w * bf2f(hv >> 16);
    }
    __shared__ float sa[256], sb[256];
    sa[t] = a0; sb[t] = a1;
    __syncthreads();
    if (t < 128) {
        float v0 = sa[t] + sa[t + 128];
        float v1 = sb[t] + sb[t + 128];
        float2 inv = invden[n];
        float iv = (t >> 6) ? inv.y : inv.x;
        float2 b = reinterpret_cast<const float2*>(bias)[t];
        float o0 = v0 * iv + b.x;
        float o1 = v1 * iv + b.y;
        if (do_relu) { o0 = fmaxf(o0, 0.f); o1 = fmaxf(o1, 0.f); }
        outb2[(size_t)n * 128 + t] = (uint)f2bf(o0) | ((uint)f2bf(o1) << 16);
    }
}

// ---------------------------------------------------------------------------
// final: out = sigmoid(h2 @ Wf + bf), wave per node
// ---------------------------------------------------------------------------
__global__ __launch_bounds__(256) void gemv_kernel(const uint* __restrict__ hb2,
                                                   const float2* __restrict__ Wf,
                                                   const float* __restrict__ bfv,
                                                   float* __restrict__ out) {
    int wave = threadIdx.x >> 6, lane = threadIdx.x & 63;
    int n = blockIdx.x * 4 + wave;
    if (n >= NNODES) return;
    uint2 p = reinterpret_cast<const uint2*>(hb2 + (size_t)n * 128)[lane];
    float f0 = bf2f(p.x & 0xffffu), f1 = bf2f(p.x >> 16);
    float f2 = bf2f(p.y & 0xffffu), f3 = bf2f(p.y >> 16);
    float4 wa = reinterpret_cast<const float4*>(Wf)[2 * lane];
    float4 wb = reinterpret_cast<const float4*>(Wf)[2 * lane + 1];
    float p0 = wred_sum(f0 * wa.x + f1 * wa.z + f2 * wb.x + f3 * wb.z);
    float p1 = wred_sum(f0 * wa.y + f1 * wa.w + f2 * wb.y + f3 * wb.w);
    if (lane == 0) {
        out[2 * n]     = 1.f / (1.f + __expf(-(p0 + bfv[0])));
        out[2 * n + 1] = 1.f / (1.f + __expf(-(p1 + bfv[1])));
    }
}

// ---------------------------------------------------------------------------
extern "C" void kernel_launch(void* const* d_in, const int* in_sizes, int n_in,
                              void* d_out, int out_size, void* d_ws, size_t ws_size,
                              hipStream_t stream) {
    const float* x      = (const float*)d_in[0];
    const int*   ei     = (const int*)d_in[1];
    const float* W1     = (const float*)d_in[2];
    const float* a_src1 = (const float*)d_in[3];
    const float* a_dst1 = (const float*)d_in[4];
    const float* b1     = (const float*)d_in[5];
    const float* W2     = (const float*)d_in[6];
    const float* a_src2 = (const float*)d_in[7];
    const float* a_dst2 = (const float*)d_in[8];
    const float* b2     = (const float*)d_in[9];
    const float* Wp1    = (const float*)d_in[10];
    const float* bp1    = (const float*)d_in[11];
    const float* Wp2    = (const float*)d_in[12];
    const float* bp2    = (const float*)d_in[13];
    float* outp = (float*)d_out;

    // workspace carve-up (all regions 16B aligned)
    char* w = (char*)d_ws;
    ushort* hbf  = (ushort*)w; w += (size_t)NPAD * 256 * sizeof(ushort);  // 51.2MB
    ushort* obf  = (ushort*)w; w += (size_t)NPAD * 256 * sizeof(ushort);  // 51.2MB
    ushort* W1t  = (ushort*)w; w += (size_t)256 * 128 * sizeof(ushort);
    ushort* W2t  = (ushort*)w; w += (size_t)256 * 256 * sizeof(ushort);
    float2* Wf   = (float2*)w; w += 256 * sizeof(float2);
    float*  bfv  = (float*)w;  w += 4 * sizeof(float);
    float2* as_  = (float2*)w; w += (size_t)NPAD * sizeof(float2);        // zeroed
    float2* ad_  = (float2*)w; w += (size_t)NPAD * sizeof(float2);        // zeroed
    float2* ew   = (float2*)w; w += (size_t)ETOT * sizeof(float2);        // 7.2MB
    float2* invd = (float2*)w; w += (size_t)NNODES * sizeof(float2);
    int* deg       = (int*)w; w += (size_t)NNODES * sizeof(int);
    int* row_start = (int*)w; w += (size_t)(NNODES + 16) * sizeof(int);
    int* cursor    = (int*)w; w += (size_t)NNODES * sizeof(int);
    int* csr_src   = (int*)w; w += (size_t)ETOT * sizeof(int);
    int* bsum      = (int*)w; w += 512 * sizeof(int);
    int* bsum2     = (int*)w; w += 512 * sizeof(int);

    const int SCAN_BLOCKS = (NNODES + 255) / 256;   // 391
    const int NODE_WAVES  = (NNODES + 3) / 4;       // 25000
    const int MB = NPAD / 64;                       // 1563
    const size_t ALPHA_BYTES = 2 * (size_t)NPAD * sizeof(float2);  // as_ + ad_

    // --- CSR build ---
    hipMemsetAsync(deg, 0, (size_t)NNODES * sizeof(int), stream);
    hist_kernel<<<(ETOT + 255) / 256, 256, 0, stream>>>(ei, deg);
    scan1_kernel<<<SCAN_BLOCKS, 256, 0, stream>>>(deg, row_start, bsum);
    scan2_kernel<<<1, 512, 0, stream>>>(bsum, bsum2, SCAN_BLOCKS);
    scan3_kernel<<<SCAN_BLOCKS, 256, 0, stream>>>(row_start, bsum2, cursor);
    scatter_kernel<<<(ETOT + 255) / 256, 256, 0, stream>>>(ei, cursor, csr_src);

    // --- weight prep ---
    transpose_bf_kernel<<<(128 * 256 + 255) / 256, 256, 0, stream>>>(W1, W1t, 128, 256);
    transpose_bf_kernel<<<(256 * 256 + 255) / 256, 256, 0, stream>>>(W2, W2t, 256, 256);
    fw_kernel<<<1, 256, 0, stream>>>(Wp1, bp1, Wp2, bp2, Wf, bfv);

    // --- layer 1 ---
    hipMemsetAsync(as_, 0, ALPHA_BYTES, stream);
    mfma_gemm_f32A<<<dim3(MB, 4), 256, 0, stream>>>(x, W1t, hbf, (float*)as_, (float*)ad_,
                                                    a_src1, a_dst1, 256, 128);
    weights_kernel<<<SCAN_BLOCKS, 256, 0, stream>>>(as_, ad_, row_start, csr_src, ew, invd);
    gather_kernel<<<NNODES, 256, 0, stream>>>((const uint*)hbf, row_start, csr_src, ew, invd,
                                              b1, (uint*)obf, 1);

    // --- layer 2 ---
    hipMemsetAsync(as_, 0, ALPHA_BYTES, stream);
    mfma_gemm_bf16A<<<dim3(MB, 4), 256, 0, stream>>>(obf, W2t, hbf, (float*)as_, (float*)ad_,
                                                     a_src2, a_dst2, 256, 256);
    weights_kernel<<<SCAN_BLOCKS, 256, 0, stream>>>(as_, ad_, row_start, csr_src, ew, invd);
    gather_kernel<<<NNODES, 256, 0, stream>>>((const uint*)hbf, row_start, csr_src, ew, invd,
                                              b2, (uint*)obf, 1);

    // --- fused post_mp: sigmoid(h @ (Wp1@Wp2) + (bp1@Wp2+bp2)) ---
    gemv_kernel<<<NODE_WAVES, 256, 0, stream>>>((const uint*)obf, Wf, bfv, outp);
}

// Round 4
// 485.345 us; speedup vs baseline: 2.4977x; 1.3256x over previous
//
#include <hip/hip_runtime.h>
#include <hip/hip_bf16.h>
#include <math.h>

// Problem constants (match reference)
#define NNODES 100000
#define NPAD   100032        // padded to multiple of 64 for guard-free GEMM
#define IN_DIM 128
#define HID 128
#define HEADS 2
#define F2 256               // HEADS*HID
#define NEDGES 800000
#define ETOT 900000          // NEDGES + NNODES self-loops
#define NEG_SLOPE 0.2f

typedef unsigned int uint;
typedef unsigned short ushort;
typedef __attribute__((ext_vector_type(8))) short short8;
typedef __attribute__((ext_vector_type(4))) float floatx4;

__device__ __forceinline__ ushort f2bf(float f) {
    uint u = __builtin_bit_cast(uint, f);
    u += 0x7fffu + ((u >> 16) & 1u);       // round-to-nearest-even
    return (ushort)(u >> 16);
}
__device__ __forceinline__ float bf2f(uint u16) {
    return __builtin_bit_cast(float, u16 << 16);
}
__device__ __forceinline__ float wred_sum(float v) {
    for (int o = 32; o; o >>= 1) v += __shfl_xor(v, o);
    return v;
}

// ---------------------------------------------------------------------------
// CSR build: histogram -> scan -> scatter
// ---------------------------------------------------------------------------
__global__ __launch_bounds__(256) void hist_kernel(const int* __restrict__ ei,
                                                   int* __restrict__ deg) {
    int i = blockIdx.x * 256 + threadIdx.x;
    if (i >= ETOT) return;
    int dst = (i < NEDGES) ? ei[NEDGES + i] : (i - NEDGES);
    atomicAdd(&deg[dst], 1);
}

__global__ __launch_bounds__(256) void scan1_kernel(const int* __restrict__ deg,
                                                    int* __restrict__ row_start,
                                                    int* __restrict__ bsum) {
    __shared__ int s[256];
    int t = threadIdx.x;
    int i = blockIdx.x * 256 + t;
    int v = (i < NNODES) ? deg[i] : 0;
    s[t] = v;
    __syncthreads();
    for (int off = 1; off < 256; off <<= 1) {
        int x = (t >= off) ? s[t - off] : 0;
        __syncthreads();
        s[t] += x;
        __syncthreads();
    }
    if (i < NNODES) row_start[i] = s[t] - v;   // exclusive
    if (t == 255) bsum[blockIdx.x] = s[255];
}

__global__ __launch_bounds__(512) void scan2_kernel(const int* __restrict__ bsum,
                                                    int* __restrict__ bsum2,
                                                    int cnt) {
    __shared__ int s[512];
    int t = threadIdx.x;
    int v = (t < cnt) ? bsum[t] : 0;
    s[t] = v;
    __syncthreads();
    for (int off = 1; off < 512; off <<= 1) {
        int x = (t >= off) ? s[t - off] : 0;
        __syncthreads();
        s[t] += x;
        __syncthreads();
    }
    bsum2[t] = s[t] - v;   // exclusive
}

__global__ __launch_bounds__(256) void scan3_kernel(int* __restrict__ row_start,
                                                    const int* __restrict__ bsum2,
                                                    int* __restrict__ cursor) {
    int i = blockIdx.x * 256 + threadIdx.x;
    if (i == 0) row_start[NNODES] = ETOT;
    if (i >= NNODES) return;
    int r = row_start[i] + bsum2[i >> 8];
    row_start[i] = r;
    cursor[i] = r;
}

__global__ __launch_bounds__(256) void scatter_kernel(const int* __restrict__ ei,
                                                      int* __restrict__ cursor,
                                                      int* __restrict__ csr_src) {
    int i = blockIdx.x * 256 + threadIdx.x;
    if (i >= ETOT) return;
    int src, dst;
    if (i < NEDGES) { src = ei[i]; dst = ei[NEDGES + i]; }
    else            { src = i - NEDGES; dst = src; }
    int pos = atomicAdd(&cursor[dst], 1);
    csr_src[pos] = src;
}

// ---------------------------------------------------------------------------
// W[K][N] fp32 -> Wt[N][K] bf16   (weights are tiny; naive is fine)
// ---------------------------------------------------------------------------
__global__ __launch_bounds__(256) void transpose_bf_kernel(const float* __restrict__ W,
                                                           ushort* __restrict__ Wt,
                                                           int K, int N) {
    int i = blockIdx.x * 256 + threadIdx.x;
    if (i >= K * N) return;
    int n = i / K, k = i - n * K;
    Wt[(size_t)n * K + k] = f2bf(W[(size_t)k * N + n]);
}

// Wf[k][0:2] = Wp1[k][:] @ Wp2 ; bf[j] = bp1 @ Wp2[:,j] + bp2[j]   (1 block)
__global__ __launch_bounds__(256) void fw_kernel(const float* __restrict__ Wp1,
                                                 const float* __restrict__ bp1,
                                                 const float* __restrict__ Wp2,
                                                 const float* __restrict__ bp2,
                                                 float2* __restrict__ Wf,
                                                 float* __restrict__ bfv) {
    int k = threadIdx.x;   // 0..255
    float s0 = 0.f, s1 = 0.f;
    for (int m = 0; m < 128; m++) {
        float w = Wp1[(size_t)k * 128 + m];
        s0 += w * Wp2[2 * m];
        s1 += w * Wp2[2 * m + 1];
    }
    Wf[k] = make_float2(s0, s1);
    if (k < 2) {
        float b = bp2[k];
        for (int m = 0; m < 128; m++) b += bp1[m] * Wp2[2 * m + k];
        bfv[k] = b;
    }
}

// ---------------------------------------------------------------------------
// bf16 MFMA GEMM (A fp32, converted in staging): C = A @ Bt^T, fused alpha
// logits (as_[row,head] += sum_c C[row,c]*a_src[c] over this block's cols).
// block tile 64x64, 4 waves (wave: 16 rows x 64 cols), BK=32
// ---------------------------------------------------------------------------
__global__ __launch_bounds__(256) void mfma_gemm_f32A(const float* __restrict__ A,
                                                      const ushort* __restrict__ Bt,
                                                      ushort* __restrict__ C,
                                                      float* __restrict__ as_f,
                                                      float* __restrict__ ad_f,
                                                      const float* __restrict__ aS,
                                                      const float* __restrict__ aD,
                                                      int N, int K) {
    __shared__ ushort As[64][40];
    __shared__ ushort Bs[64][40];
    int t = threadIdx.x;
    int wave = t >> 6, lane = t & 63;
    int quad = lane >> 4, l16 = lane & 15;
    size_t rowBase = (size_t)blockIdx.x * 64;
    int colBase = blockIdx.y * 64;

    floatx4 acc[4];
#pragma unroll
    for (int i = 0; i < 4; i++) acc[i] = (floatx4){0.f, 0.f, 0.f, 0.f};

    int ar = t >> 2, ac = (t & 3) * 8;
    int agr = (int)rowBase + ar;
    const float*  Ap = A + (size_t)agr * K + ac;
    const ushort* Bp = Bt + (size_t)(colBase + ar) * K + ac;
    bool aok = agr < NNODES;

    for (int k0 = 0; k0 < K; k0 += 32) {
        float4 f0 = make_float4(0.f, 0.f, 0.f, 0.f), f1 = f0;
        if (aok) {
            f0 = *reinterpret_cast<const float4*>(Ap + k0);
            f1 = *reinterpret_cast<const float4*>(Ap + k0 + 4);
        }
        uint4 bv = *reinterpret_cast<const uint4*>(Bp + k0);
        uint u0 = (uint)f2bf(f0.x) | ((uint)f2bf(f0.y) << 16);
        uint u1 = (uint)f2bf(f0.z) | ((uint)f2bf(f0.w) << 16);
        uint u2 = (uint)f2bf(f1.x) | ((uint)f2bf(f1.y) << 16);
        uint u3 = (uint)f2bf(f1.z) | ((uint)f2bf(f1.w) << 16);
        *reinterpret_cast<uint2*>(&As[ar][ac])     = make_uint2(u0, u1);
        *reinterpret_cast<uint2*>(&As[ar][ac + 4]) = make_uint2(u2, u3);
        *reinterpret_cast<uint2*>(&Bs[ar][ac])     = make_uint2(bv.x, bv.y);
        *reinterpret_cast<uint2*>(&Bs[ar][ac + 4]) = make_uint2(bv.z, bv.w);
        __syncthreads();

        union { uint2 u[2]; short8 s; } afr, bfr;
        afr.u[0] = *reinterpret_cast<const uint2*>(&As[wave * 16 + l16][quad * 8]);
        afr.u[1] = *reinterpret_cast<const uint2*>(&As[wave * 16 + l16][quad * 8 + 4]);
#pragma unroll
        for (int nt = 0; nt < 4; nt++) {
            bfr.u[0] = *reinterpret_cast<const uint2*>(&Bs[nt * 16 + l16][quad * 8]);
            bfr.u[1] = *reinterpret_cast<const uint2*>(&Bs[nt * 16 + l16][quad * 8 + 4]);
            acc[nt] = __builtin_amdgcn_mfma_f32_16x16x32_bf16(afr.s, bfr.s, acc[nt], 0, 0, 0);
        }
        __syncthreads();
    }

    // C write: D row = quad*4+reg, col = l16 within 16x16 tile
#pragma unroll
    for (int nt = 0; nt < 4; nt++) {
        int col = colBase + nt * 16 + l16;
#pragma unroll
        for (int r = 0; r < 4; r++) {
            size_t row = rowBase + wave * 16 + quad * 4 + r;
            C[row * N + col] = f2bf(acc[nt][r]);
        }
    }
    // fused alpha logits: partial over this block's 64 cols, head uniform
    int head = colBase >> 7;
#pragma unroll
    for (int r = 0; r < 4; r++) {
        float ps = 0.f, pd = 0.f;
#pragma unroll
        for (int nt = 0; nt < 4; nt++) {
            int c = colBase + nt * 16 + l16;
            ps += acc[nt][r] * aS[c];
            pd += acc[nt][r] * aD[c];
        }
#pragma unroll
        for (int o = 1; o < 16; o <<= 1) {
            ps += __shfl_xor(ps, o);
            pd += __shfl_xor(pd, o);
        }
        if (l16 == 0) {
            size_t row = rowBase + wave * 16 + quad * 4 + r;
            atomicAdd(&as_f[2 * row + head], ps);
            atomicAdd(&ad_f[2 * row + head], pd);
        }
    }
}

// same but A already bf16 (padded, no guard)
__global__ __launch_bounds__(256) void mfma_gemm_bf16A(const ushort* __restrict__ A,
                                                       const ushort* __restrict__ Bt,
                                                       ushort* __restrict__ C,
                                                       float* __restrict__ as_f,
                                                       float* __restrict__ ad_f,
                                                       const float* __restrict__ aS,
                                                       const float* __restrict__ aD,
                                                       int N, int K) {
    __shared__ ushort As[64][40];
    __shared__ ushort Bs[64][40];
    int t = threadIdx.x;
    int wave = t >> 6, lane = t & 63;
    int quad = lane >> 4, l16 = lane & 15;
    size_t rowBase = (size_t)blockIdx.x * 64;
    int colBase = blockIdx.y * 64;

    floatx4 acc[4];
#pragma unroll
    for (int i = 0; i < 4; i++) acc[i] = (floatx4){0.f, 0.f, 0.f, 0.f};

    int ar = t >> 2, ac = (t & 3) * 8;
    const ushort* Ap = A + ((size_t)blockIdx.x * 64 + ar) * K + ac;
    const ushort* Bp = Bt + (size_t)(colBase + ar) * K + ac;

    for (int k0 = 0; k0 < K; k0 += 32) {
        uint4 av = *reinterpret_cast<const uint4*>(Ap + k0);
        uint4 bv = *reinterpret_cast<const uint4*>(Bp + k0);
        *reinterpret_cast<uint2*>(&As[ar][ac])     = make_uint2(av.x, av.y);
        *reinterpret_cast<uint2*>(&As[ar][ac + 4]) = make_uint2(av.z, av.w);
        *reinterpret_cast<uint2*>(&Bs[ar][ac])     = make_uint2(bv.x, bv.y);
        *reinterpret_cast<uint2*>(&Bs[ar][ac + 4]) = make_uint2(bv.z, bv.w);
        __syncthreads();

        union { uint2 u[2]; short8 s; } afr, bfr;
        afr.u[0] = *reinterpret_cast<const uint2*>(&As[wave * 16 + l16][quad * 8]);
        afr.u[1] = *reinterpret_cast<const uint2*>(&As[wave * 16 + l16][quad * 8 + 4]);
#pragma unroll
        for (int nt = 0; nt < 4; nt++) {
            bfr.u[0] = *reinterpret_cast<const uint2*>(&Bs[nt * 16 + l16][quad * 8]);
            bfr.u[1] = *reinterpret_cast<const uint2*>(&Bs[nt * 16 + l16][quad * 8 + 4]);
            acc[nt] = __builtin_amdgcn_mfma_f32_16x16x32_bf16(afr.s, bfr.s, acc[nt], 0, 0, 0);
        }
        __syncthreads();
    }

#pragma unroll
    for (int nt = 0; nt < 4; nt++) {
        int col = colBase + nt * 16 + l16;
#pragma unroll
        for (int r = 0; r < 4; r++) {
            size_t row = rowBase + wave * 16 + quad * 4 + r;
            C[row * N + col] = f2bf(acc[nt][r]);
        }
    }
    int head = colBase >> 7;
#pragma unroll
    for (int r = 0; r < 4; r++) {
        float ps = 0.f, pd = 0.f;
#pragma unroll
        for (int nt = 0; nt < 4; nt++) {
            int c = colBase + nt * 16 + l16;
            ps += acc[nt][r] * aS[c];
            pd += acc[nt][r] * aD[c];
        }
#pragma unroll
        for (int o = 1; o < 16; o <<= 1) {
            ps += __shfl_xor(ps, o);
            pd += __shfl_xor(pd, o);
        }
        if (l16 == 0) {
            size_t row = rowBase + wave * 16 + quad * 4 + r;
            atomicAdd(&as_f[2 * row + head], ps);
            atomicAdd(&ad_f[2 * row + head], pd);
        }
    }
}

// ---------------------------------------------------------------------------
// fully-fused segment softmax + weighted gather. Wave per node, no LDS,
// no __syncthreads, no max-shift (logits are O(1); exp(e)/sum(exp(e)) is
// shift-invariant and fp32-safe here).
// lane owns features 4*lane..4*lane+3 (uint2 of h). 4 edges in flight.
// ---------------------------------------------------------------------------
__device__ __forceinline__ float edge_w(float2 q, float2 ad, int hsel) {
    float l = hsel ? (q.y + ad.y) : (q.x + ad.x);
    l = l > 0.f ? l : NEG_SLOPE * l;
    return __expf(l);
}

__global__ __launch_bounds__(256) void gather_kernel(const uint2* __restrict__ hb2,
                                                     const int* __restrict__ row_start,
                                                     const int* __restrict__ csr_src,
                                                     const float2* __restrict__ as_,
                                                     const float2* __restrict__ ad_,
                                                     const float4* __restrict__ bias4,
                                                     uint2* __restrict__ outb2) {
    int wave = threadIdx.x >> 6, lane = threadIdx.x & 63;
    int n = blockIdx.x * 4 + wave;
    if (n >= NNODES) return;
    int beg = row_start[n], end = row_start[n + 1];
    float2 ad = ad_[n];
    int hsel = lane >> 5;    // lanes 0-31: head 0 (features 0..127), 32-63: head 1
    float a0 = 0.f, a1 = 0.f, a2 = 0.f, a3 = 0.f, den = 0.f;

    int j = beg;
    for (; j + 3 < end; j += 4) {
        int s0 = csr_src[j],     s1 = csr_src[j + 1];
        int s2 = csr_src[j + 2], s3 = csr_src[j + 3];
        float2 q0 = as_[s0], q1 = as_[s1], q2 = as_[s2], q3 = as_[s3];
        uint2 h0 = hb2[(size_t)s0 * 64 + lane];
        uint2 h1 = hb2[(size_t)s1 * 64 + lane];
        uint2 h2 = hb2[(size_t)s2 * 64 + lane];
        uint2 h3 = hb2[(size_t)s3 * 64 + lane];
        float w0 = edge_w(q0, ad, hsel), w1 = edge_w(q1, ad, hsel);
        float w2 = edge_w(q2, ad, hsel), w3 = edge_w(q3, ad, hsel);
        den += (w0 + w1) + (w2 + w3);
        a0 += w0 * bf2f(h0.x & 0xffffu) + w1 * bf2f(h1.x & 0xffffu)
            + w2 * bf2f(h2.x & 0xffffu) + w3 * bf2f(h3.x & 0xffffu);
        a1 += w0 * bf2f(h0.x >> 16) + w1 * bf2f(h1.x >> 16)
            + w2 * bf2f(h2.x >> 16) + w3 * bf2f(h3.x >> 16);
        a2 += w0 * bf2f(h0.y & 0xffffu) + w1 * bf2f(h1.y & 0xffffu)
            + w2 * bf2f(h2.y & 0xffffu) + w3 * bf2f(h3.y & 0xffffu);
        a3 += w0 * bf2f(h0.y >> 16) + w1 * bf2f(h1.y >> 16)
            + w2 * bf2f(h2.y >> 16) + w3 * bf2f(h3.y >> 16);
    }
    for (; j < end; j++) {
        int s = csr_src[j];
        float2 q = as_[s];
        uint2 hv = hb2[(size_t)s * 64 + lane];
        float w = edge_w(q, ad, hsel);
        den += w;
        a0 += w * bf2f(hv.x & 0xffffu);
        a1 += w * bf2f(hv.x >> 16);
        a2 += w * bf2f(hv.y & 0xffffu);
        a3 += w * bf2f(hv.y >> 16);
    }
    float inv = 1.f / (den + 1e-16f);
    float4 b = bias4[lane];
    float o0 = fmaxf(a0 * inv + b.x, 0.f);
    float o1 = fmaxf(a1 * inv + b.y, 0.f);
    float o2 = fmaxf(a2 * inv + b.z, 0.f);
    float o3 = fmaxf(a3 * inv + b.w, 0.f);
    uint2 pk;
    pk.x = (uint)f2bf(o0) | ((uint)f2bf(o1) << 16);
    pk.y = (uint)f2bf(o2) | ((uint)f2bf(o3) << 16);
    outb2[(size_t)n * 64 + lane] = pk;
}

// ---------------------------------------------------------------------------
// final: out = sigmoid(h2 @ Wf + bf), wave per node
// ---------------------------------------------------------------------------
__global__ __launch_bounds__(256) void gemv_kernel(const uint* __restrict__ hb2,
                                                   const float2* __restrict__ Wf,
                                                   const float* __restrict__ bfv,
                                                   float* __restrict__ out) {
    int wave = threadIdx.x >> 6, lane = threadIdx.x & 63;
    int n = blockIdx.x * 4 + wave;
    if (n >= NNODES) return;
    uint2 p = reinterpret_cast<const uint2*>(hb2 + (size_t)n * 128)[lane];
    float f0 = bf2f(p.x & 0xffffu), f1 = bf2f(p.x >> 16);
    float f2 = bf2f(p.y & 0xffffu), f3 = bf2f(p.y >> 16);
    float4 wa = reinterpret_cast<const float4*>(Wf)[2 * lane];
    float4 wb = reinterpret_cast<const float4*>(Wf)[2 * lane + 1];
    float p0 = wred_sum(f0 * wa.x + f1 * wa.z + f2 * wb.x + f3 * wb.z);
    float p1 = wred_sum(f0 * wa.y + f1 * wa.w + f2 * wb.y + f3 * wb.w);
    if (lane == 0) {
        out[2 * n]     = 1.f / (1.f + __expf(-(p0 + bfv[0])));
        out[2 * n + 1] = 1.f / (1.f + __expf(-(p1 + bfv[1])));
    }
}

// ---------------------------------------------------------------------------
extern "C" void kernel_launch(void* const* d_in, const int* in_sizes, int n_in,
                              void* d_out, int out_size, void* d_ws, size_t ws_size,
                              hipStream_t stream) {
    const float* x      = (const float*)d_in[0];
    const int*   ei     = (const int*)d_in[1];
    const float* W1     = (const float*)d_in[2];
    const float* a_src1 = (const float*)d_in[3];
    const float* a_dst1 = (const float*)d_in[4];
    const float* b1     = (const float*)d_in[5];
    const float* W2     = (const float*)d_in[6];
    const float* a_src2 = (const float*)d_in[7];
    const float* a_dst2 = (const float*)d_in[8];
    const float* b2     = (const float*)d_in[9];
    const float* Wp1    = (const float*)d_in[10];
    const float* bp1    = (const float*)d_in[11];
    const float* Wp2    = (const float*)d_in[12];
    const float* bp2    = (const float*)d_in[13];
    float* outp = (float*)d_out;

    // workspace carve-up (all regions 16B aligned)
    char* w = (char*)d_ws;
    ushort* hbf  = (ushort*)w; w += (size_t)NPAD * 256 * sizeof(ushort);  // 51.2MB
    ushort* obf  = (ushort*)w; w += (size_t)NPAD * 256 * sizeof(ushort);  // 51.2MB
    ushort* W1t  = (ushort*)w; w += (size_t)256 * 128 * sizeof(ushort);
    ushort* W2t  = (ushort*)w; w += (size_t)256 * 256 * sizeof(ushort);
    float2* Wf   = (float2*)w; w += 256 * sizeof(float2);
    float*  bfv  = (float*)w;  w += 4 * sizeof(float);
    float2* as_  = (float2*)w; w += (size_t)NPAD * sizeof(float2);        // zeroed
    float2* ad_  = (float2*)w; w += (size_t)NPAD * sizeof(float2);        // zeroed
    int* deg       = (int*)w; w += (size_t)NNODES * sizeof(int);
    int* row_start = (int*)w; w += (size_t)(NNODES + 16) * sizeof(int);
    int* cursor    = (int*)w; w += (size_t)NNODES * sizeof(int);
    int* csr_src   = (int*)w; w += (size_t)ETOT * sizeof(int);
    int* bsum      = (int*)w; w += 512 * sizeof(int);
    int* bsum2     = (int*)w; w += 512 * sizeof(int);

    const int SCAN_BLOCKS = (NNODES + 255) / 256;   // 391
    const int NODE_WAVES  = (NNODES + 3) / 4;       // 25000
    const int MB = NPAD / 64;                       // 1563
    const size_t ALPHA_BYTES = 2 * (size_t)NPAD * sizeof(float2);  // as_ + ad_

    // --- CSR build ---
    hipMemsetAsync(deg, 0, (size_t)NNODES * sizeof(int), stream);
    hist_kernel<<<(ETOT + 255) / 256, 256, 0, stream>>>(ei, deg);
    scan1_kernel<<<SCAN_BLOCKS, 256, 0, stream>>>(deg, row_start, bsum);
    scan2_kernel<<<1, 512, 0, stream>>>(bsum, bsum2, SCAN_BLOCKS);
    scan3_kernel<<<SCAN_BLOCKS, 256, 0, stream>>>(row_start, bsum2, cursor);
    scatter_kernel<<<(ETOT + 255) / 256, 256, 0, stream>>>(ei, cursor, csr_src);

    // --- weight prep ---
    transpose_bf_kernel<<<(128 * 256 + 255) / 256, 256, 0, stream>>>(W1, W1t, 128, 256);
    transpose_bf_kernel<<<(256 * 256 + 255) / 256, 256, 0, stream>>>(W2, W2t, 256, 256);
    fw_kernel<<<1, 256, 0, stream>>>(Wp1, bp1, Wp2, bp2, Wf, bfv);

    // --- layer 1 ---
    hipMemsetAsync(as_, 0, ALPHA_BYTES, stream);
    mfma_gemm_f32A<<<dim3(MB, 4), 256, 0, stream>>>(x, W1t, hbf, (float*)as_, (float*)ad_,
                                                    a_src1, a_dst1, 256, 128);
    gather_kernel<<<NODE_WAVES, 256, 0, stream>>>((const uint2*)hbf, row_start, csr_src,
                                                  as_, ad_, (const float4*)b1, (uint2*)obf);

    // --- layer 2 ---
    hipMemsetAsync(as_, 0, ALPHA_BYTES, stream);
    mfma_gemm_bf16A<<<dim3(MB, 4), 256, 0, stream>>>(obf, W2t, hbf, (float*)as_, (float*)ad_,
                                                     a_src2, a_dst2, 256, 256);
    gather_kernel<<<NODE_WAVES, 256, 0, stream>>>((const uint2*)hbf, row_start, csr_src,
                                                  as_, ad_, (const float4*)b2, (uint2*)obf);

    // --- fused post_mp: sigmoid(h @ (Wp1@Wp2) + (bp1@Wp2+bp2)) ---
    gemv_kernel<<<NODE_WAVES, 256, 0, stream>>>((const uint*)obf, Wf, bfv, outp);
}

// Round 5
// 448.660 us; speedup vs baseline: 2.7019x; 1.0818x over previous
//
#include <hip/hip_runtime.h>
#include <hip/hip_bf16.h>
#include <math.h>

// Problem constants (match reference)
#define NNODES 100000
#define NPAD   100032        // padded to multiple of 64 for guard-free GEMM
#define IN_DIM 128
#define HID 128
#define HEADS 2
#define F2 256               // HEADS*HID
#define NEDGES 800000
#define ETOT 900000          // NEDGES + NNODES self-loops
#define NEG_SLOPE 0.2f

typedef unsigned int uint;
typedef unsigned short ushort;
typedef __attribute__((ext_vector_type(8))) short short8;
typedef __attribute__((ext_vector_type(4))) float floatx4;

__device__ __forceinline__ ushort f2bf(float f) {
    uint u = __builtin_bit_cast(uint, f);
    u += 0x7fffu + ((u >> 16) & 1u);       // round-to-nearest-even
    return (ushort)(u >> 16);
}
__device__ __forceinline__ float bf2f(uint u16) {
    return __builtin_bit_cast(float, u16 << 16);
}
__device__ __forceinline__ float wred_sum(float v) {
    for (int o = 32; o; o >>= 1) v += __shfl_xor(v, o);
    return v;
}

// ---------------------------------------------------------------------------
// CSR build: histogram -> scan -> scatter
// ---------------------------------------------------------------------------
__global__ __launch_bounds__(256) void hist_kernel(const int* __restrict__ ei,
                                                   int* __restrict__ deg) {
    int i = blockIdx.x * 256 + threadIdx.x;
    if (i >= ETOT) return;
    int dst = (i < NEDGES) ? ei[NEDGES + i] : (i - NEDGES);
    atomicAdd(&deg[dst], 1);
}

__global__ __launch_bounds__(256) void scan1_kernel(const int* __restrict__ deg,
                                                    int* __restrict__ row_start,
                                                    int* __restrict__ bsum) {
    __shared__ int s[256];
    int t = threadIdx.x;
    int i = blockIdx.x * 256 + t;
    int v = (i < NNODES) ? deg[i] : 0;
    s[t] = v;
    __syncthreads();
    for (int off = 1; off < 256; off <<= 1) {
        int x = (t >= off) ? s[t - off] : 0;
        __syncthreads();
        s[t] += x;
        __syncthreads();
    }
    if (i < NNODES) row_start[i] = s[t] - v;   // exclusive
    if (t == 255) bsum[blockIdx.x] = s[255];
}

__global__ __launch_bounds__(512) void scan2_kernel(const int* __restrict__ bsum,
                                                    int* __restrict__ bsum2,
                                                    int cnt) {
    __shared__ int s[512];
    int t = threadIdx.x;
    int v = (t < cnt) ? bsum[t] : 0;
    s[t] = v;
    __syncthreads();
    for (int off = 1; off < 512; off <<= 1) {
        int x = (t >= off) ? s[t - off] : 0;
        __syncthreads();
        s[t] += x;
        __syncthreads();
    }
    bsum2[t] = s[t] - v;   // exclusive
}

__global__ __launch_bounds__(256) void scan3_kernel(int* __restrict__ row_start,
                                                    const int* __restrict__ bsum2,
                                                    int* __restrict__ cursor) {
    int i = blockIdx.x * 256 + threadIdx.x;
    if (i == 0) row_start[NNODES] = ETOT;
    if (i >= NNODES) return;
    int r = row_start[i] + bsum2[i >> 8];
    row_start[i] = r;
    cursor[i] = r;
}

__global__ __launch_bounds__(256) void scatter_kernel(const int* __restrict__ ei,
                                                      int* __restrict__ cursor,
                                                      int* __restrict__ csr_src) {
    int i = blockIdx.x * 256 + threadIdx.x;
    if (i >= ETOT) return;
    int src, dst;
    if (i < NEDGES) { src = ei[i]; dst = ei[NEDGES + i]; }
    else            { src = i - NEDGES; dst = src; }
    int pos = atomicAdd(&cursor[dst], 1);
    csr_src[pos] = src;
}

// ---------------------------------------------------------------------------
// W[K][N] fp32 -> Wt[N][K] bf16
// ---------------------------------------------------------------------------
__global__ __launch_bounds__(256) void transpose_bf_kernel(const float* __restrict__ W,
                                                           ushort* __restrict__ Wt,
                                                           int K, int N) {
    int i = blockIdx.x * 256 + threadIdx.x;
    if (i >= K * N) return;
    int n = i / K, k = i - n * K;
    Wt[(size_t)n * K + k] = f2bf(W[(size_t)k * N + n]);
}

// Wf[k][0:2] = Wp1[k][:] @ Wp2 ; bf[j] = bp1 @ Wp2[:,j] + bp2[j]   (1 block)
__global__ __launch_bounds__(256) void fw_kernel(const float* __restrict__ Wp1,
                                                 const float* __restrict__ bp1,
                                                 const float* __restrict__ Wp2,
                                                 const float* __restrict__ bp2,
                                                 float2* __restrict__ Wf,
                                                 float* __restrict__ bfv) {
    int k = threadIdx.x;   // 0..255
    float s0 = 0.f, s1 = 0.f;
    for (int m = 0; m < 128; m++) {
        float w = Wp1[(size_t)k * 128 + m];
        s0 += w * Wp2[2 * m];
        s1 += w * Wp2[2 * m + 1];
    }
    Wf[k] = make_float2(s0, s1);
    if (k < 2) {
        float b = bp2[k];
        for (int m = 0; m < 128; m++) b += bp1[m] * Wp2[2 * m + k];
        bfv[k] = b;
    }
}

// ---------------------------------------------------------------------------
// bf16 MFMA GEMM, block tile 64 rows x 128 cols (one full head per block y).
// 4 waves: wave w = rows w*16..w*16+15, all 128 cols (8 MFMA per BK=32).
// Fused alpha logits written NON-atomically (block covers the whole head).
// ---------------------------------------------------------------------------
__global__ __launch_bounds__(256) void mfma_gemm_f32A(const float* __restrict__ A,
                                                      const ushort* __restrict__ Bt,
                                                      ushort* __restrict__ C,
                                                      float* __restrict__ as_f,
                                                      float* __restrict__ ad_f,
                                                      const float* __restrict__ aS,
                                                      const float* __restrict__ aD,
                                                      int K) {
    __shared__ ushort As[64][40];
    __shared__ ushort Bs[128][40];
    int t = threadIdx.x;
    int wave = t >> 6, lane = t & 63;
    int quad = lane >> 4, l16 = lane & 15;
    size_t rowBase = (size_t)blockIdx.x * 64;
    int colBase = blockIdx.y * 128;
    int head = blockIdx.y;

    floatx4 acc[8];
#pragma unroll
    for (int i = 0; i < 8; i++) acc[i] = (floatx4){0.f, 0.f, 0.f, 0.f};

    int ar = t >> 2, ac = (t & 3) * 8;
    int agr = (int)rowBase + ar;
    const float*  Ap  = A + (size_t)agr * K + ac;
    const ushort* Bp0 = Bt + (size_t)(colBase + ar) * K + ac;
    const ushort* Bp1 = Bp0 + (size_t)64 * K;
    bool aok = agr < NNODES;

    for (int k0 = 0; k0 < K; k0 += 32) {
        float4 f0 = make_float4(0.f, 0.f, 0.f, 0.f), f1 = f0;
        if (aok) {
            f0 = *reinterpret_cast<const float4*>(Ap + k0);
            f1 = *reinterpret_cast<const float4*>(Ap + k0 + 4);
        }
        uint4 b0 = *reinterpret_cast<const uint4*>(Bp0 + k0);
        uint4 b1 = *reinterpret_cast<const uint4*>(Bp1 + k0);
        uint4 av;
        av.x = (uint)f2bf(f0.x) | ((uint)f2bf(f0.y) << 16);
        av.y = (uint)f2bf(f0.z) | ((uint)f2bf(f0.w) << 16);
        av.z = (uint)f2bf(f1.x) | ((uint)f2bf(f1.y) << 16);
        av.w = (uint)f2bf(f1.z) | ((uint)f2bf(f1.w) << 16);
        *reinterpret_cast<uint4*>(&As[ar][ac])      = av;
        *reinterpret_cast<uint4*>(&Bs[ar][ac])      = b0;
        *reinterpret_cast<uint4*>(&Bs[64 + ar][ac]) = b1;
        __syncthreads();

        union { uint4 u; short8 s; } afr, bfr;
        afr.u = *reinterpret_cast<const uint4*>(&As[wave * 16 + l16][quad * 8]);
#pragma unroll
        for (int nt = 0; nt < 8; nt++) {
            bfr.u = *reinterpret_cast<const uint4*>(&Bs[nt * 16 + l16][quad * 8]);
            acc[nt] = __builtin_amdgcn_mfma_f32_16x16x32_bf16(afr.s, bfr.s, acc[nt], 0, 0, 0);
        }
        __syncthreads();
    }

    // C write: D row = quad*4+reg, col = l16 within 16x16 tile
#pragma unroll
    for (int nt = 0; nt < 8; nt++) {
        int col = colBase + nt * 16 + l16;
#pragma unroll
        for (int r = 0; r < 4; r++) {
            size_t row = rowBase + wave * 16 + quad * 4 + r;
            C[row * F2 + col] = f2bf(acc[nt][r]);
        }
    }
    // fused alpha logits over the full head (non-atomic)
    float aSv[8], aDv[8];
#pragma unroll
    for (int nt = 0; nt < 8; nt++) {
        int c = colBase + nt * 16 + l16;
        aSv[nt] = aS[c];
        aDv[nt] = aD[c];
    }
#pragma unroll
    for (int r = 0; r < 4; r++) {
        float ps = 0.f, pd = 0.f;
#pragma unroll
        for (int nt = 0; nt < 8; nt++) {
            ps += acc[nt][r] * aSv[nt];
            pd += acc[nt][r] * aDv[nt];
        }
#pragma unroll
        for (int o = 1; o < 16; o <<= 1) {
            ps += __shfl_xor(ps, o);
            pd += __shfl_xor(pd, o);
        }
        if (l16 == 0) {
            size_t row = rowBase + wave * 16 + quad * 4 + r;
            as_f[2 * row + head] = ps;
            ad_f[2 * row + head] = pd;
        }
    }
}

// same but A already bf16 (padded, no guard)
__global__ __launch_bounds__(256) void mfma_gemm_bf16A(const ushort* __restrict__ A,
                                                       const ushort* __restrict__ Bt,
                                                       ushort* __restrict__ C,
                                                       float* __restrict__ as_f,
                                                       float* __restrict__ ad_f,
                                                       const float* __restrict__ aS,
                                                       const float* __restrict__ aD,
                                                       int K) {
    __shared__ ushort As[64][40];
    __shared__ ushort Bs[128][40];
    int t = threadIdx.x;
    int wave = t >> 6, lane = t & 63;
    int quad = lane >> 4, l16 = lane & 15;
    size_t rowBase = (size_t)blockIdx.x * 64;
    int colBase = blockIdx.y * 128;
    int head = blockIdx.y;

    floatx4 acc[8];
#pragma unroll
    for (int i = 0; i < 8; i++) acc[i] = (floatx4){0.f, 0.f, 0.f, 0.f};

    int ar = t >> 2, ac = (t & 3) * 8;
    const ushort* Ap  = A + (rowBase + ar) * K + ac;
    const ushort* Bp0 = Bt + (size_t)(colBase + ar) * K + ac;
    const ushort* Bp1 = Bp0 + (size_t)64 * K;

    for (int k0 = 0; k0 < K; k0 += 32) {
        uint4 av = *reinterpret_cast<const uint4*>(Ap + k0);
        uint4 b0 = *reinterpret_cast<const uint4*>(Bp0 + k0);
        uint4 b1 = *reinterpret_cast<const uint4*>(Bp1 + k0);
        *reinterpret_cast<uint4*>(&As[ar][ac])      = av;
        *reinterpret_cast<uint4*>(&Bs[ar][ac])      = b0;
        *reinterpret_cast<uint4*>(&Bs[64 + ar][ac]) = b1;
        __syncthreads();

        union { uint4 u; short8 s; } afr, bfr;
        afr.u = *reinterpret_cast<const uint4*>(&As[wave * 16 + l16][quad * 8]);
#pragma unroll
        for (int nt = 0; nt < 8; nt++) {
            bfr.u = *reinterpret_cast<const uint4*>(&Bs[nt * 16 + l16][quad * 8]);
            acc[nt] = __builtin_amdgcn_mfma_f32_16x16x32_bf16(afr.s, bfr.s, acc[nt], 0, 0, 0);
        }
        __syncthreads();
    }

#pragma unroll
    for (int nt = 0; nt < 8; nt++) {
        int col = colBase + nt * 16 + l16;
#pragma unroll
        for (int r = 0; r < 4; r++) {
            size_t row = rowBase + wave * 16 + quad * 4 + r;
            C[row * F2 + col] = f2bf(acc[nt][r]);
        }
    }
    float aSv[8], aDv[8];
#pragma unroll
    for (int nt = 0; nt < 8; nt++) {
        int c = colBase + nt * 16 + l16;
        aSv[nt] = aS[c];
        aDv[nt] = aD[c];
    }
#pragma unroll
    for (int r = 0; r < 4; r++) {
        float ps = 0.f, pd = 0.f;
#pragma unroll
        for (int nt = 0; nt < 8; nt++) {
            ps += acc[nt][r] * aSv[nt];
            pd += acc[nt][r] * aDv[nt];
        }
#pragma unroll
        for (int o = 1; o < 16; o <<= 1) {
            ps += __shfl_xor(ps, o);
            pd += __shfl_xor(pd, o);
        }
        if (l16 == 0) {
            size_t row = rowBase + wave * 16 + quad * 4 + r;
            as_f[2 * row + head] = ps;
            ad_f[2 * row + head] = pd;
        }
    }
}

// ---------------------------------------------------------------------------
// fully-fused segment softmax + weighted gather. Wave per node.
// Weight phase: lane j computes edge j's (w0,w1) once (coalesced csr_src).
// Feature loop: readlane broadcasts src_j (scalar h-row address) and w_j
// (SGPR fma operand). Each lane accumulates the FULL sum of its selected-head
// weights alongside -> denominator with no reduction.
// final_mode: 0 = write bf16 row (relu), 1 = fuse post_mp GEMV + sigmoid.
// ---------------------------------------------------------------------------
__global__ __launch_bounds__(256) void gather_kernel(const uint2* __restrict__ hb2,
                                                     const int* __restrict__ row_start,
                                                     const int* __restrict__ csr_src,
                                                     const float2* __restrict__ as_,
                                                     const float2* __restrict__ ad_,
                                                     const float4* __restrict__ bias4,
                                                     uint2* __restrict__ outb2,
                                                     const float4* __restrict__ WfA,
                                                     const float* __restrict__ bfv,
                                                     float2* __restrict__ outp,
                                                     int final_mode) {
    int wave = threadIdx.x >> 6, lane = threadIdx.x & 63;
    int n = blockIdx.x * 4 + wave;
    if (n >= NNODES) return;
    int beg = row_start[n], end = row_start[n + 1];
    float2 ad = ad_[n];
    bool head1 = lane >= 32;   // lanes 0-31: head0 feats, 32-63: head1 feats

    float a0 = 0.f, a1 = 0.f, a2 = 0.f, a3 = 0.f;
    float aden = 0.f;          // full selected-head weight sum (same in all lanes of a half-wave)

    for (int chunk = beg; chunk < end; chunk += 64) {
        int cnt = end - chunk;
        if (cnt > 64) cnt = 64;
        // weight phase: lane j owns edge chunk+j
        int e = chunk + lane;
        int sv = csr_src[(e < end) ? e : (end - 1)];
        float2 q = as_[sv];
        float l0 = q.x + ad.x; l0 = l0 > 0.f ? l0 : NEG_SLOPE * l0;
        float l1 = q.y + ad.y; l1 = l1 > 0.f ? l1 : NEG_SLOPE * l1;
        float w0 = __expf(l0);
        float w1 = __expf(l1);

        // feature loop: broadcast edge j's src and weights
#pragma unroll 4
        for (int j = 0; j < cnt; j++) {
            int   sj  = __builtin_amdgcn_readlane(sv, j);
            float wj0 = __builtin_bit_cast(float,
                          __builtin_amdgcn_readlane(__builtin_bit_cast(int, w0), j));
            float wj1 = __builtin_bit_cast(float,
                          __builtin_amdgcn_readlane(__builtin_bit_cast(int, w1), j));
            float wj = head1 ? wj1 : wj0;
            uint2 hv = hb2[(size_t)sj * 64 + lane];
            aden += wj;
            a0 += wj * bf2f(hv.x & 0xffffu);
            a1 += wj * bf2f(hv.x >> 16);
            a2 += wj * bf2f(hv.y & 0xffffu);
            a3 += wj * bf2f(hv.y >> 16);
        }
    }
    float inv = 1.f / (aden + 1e-16f);
    float4 b = bias4[lane];
    float o0 = fmaxf(a0 * inv + b.x, 0.f);
    float o1 = fmaxf(a1 * inv + b.y, 0.f);
    float o2 = fmaxf(a2 * inv + b.z, 0.f);
    float o3 = fmaxf(a3 * inv + b.w, 0.f);
    if (!final_mode) {
        uint2 pk;
        pk.x = (uint)f2bf(o0) | ((uint)f2bf(o1) << 16);
        pk.y = (uint)f2bf(o2) | ((uint)f2bf(o3) << 16);
        outb2[(size_t)n * 64 + lane] = pk;
    } else {
        // fused post_mp: p = o . Wf (per-lane 4 features), reduce, sigmoid
        float4 wa = WfA[2 * lane];
        float4 wb = WfA[2 * lane + 1];
        float p0 = o0 * wa.x + o1 * wa.z + o2 * wb.x + o3 * wb.z;
        float p1 = o0 * wa.y + o1 * wa.w + o2 * wb.y + o3 * wb.w;
        p0 = wred_sum(p0);
        p1 = wred_sum(p1);
        if (lane == 0) {
            float2 r;
            r.x = 1.f / (1.f + __expf(-(p0 + bfv[0])));
            r.y = 1.f / (1.f + __expf(-(p1 + bfv[1])));
            outp[n] = r;
        }
    }
}

// ---------------------------------------------------------------------------
extern "C" void kernel_launch(void* const* d_in, const int* in_sizes, int n_in,
                              void* d_out, int out_size, void* d_ws, size_t ws_size,
                              hipStream_t stream) {
    const float* x      = (const float*)d_in[0];
    const int*   ei     = (const int*)d_in[1];
    const float* W1     = (const float*)d_in[2];
    const float* a_src1 = (const float*)d_in[3];
    const float* a_dst1 = (const float*)d_in[4];
    const float* b1     = (const float*)d_in[5];
    const float* W2     = (const float*)d_in[6];
    const float* a_src2 = (const float*)d_in[7];
    const float* a_dst2 = (const float*)d_in[8];
    const float* b2     = (const float*)d_in[9];
    const float* Wp1    = (const float*)d_in[10];
    const float* bp1    = (const float*)d_in[11];
    const float* Wp2    = (const float*)d_in[12];
    const float* bp2    = (const float*)d_in[13];
    float* outp = (float*)d_out;

    // workspace carve-up (all regions 16B aligned)
    char* w = (char*)d_ws;
    ushort* hbf  = (ushort*)w; w += (size_t)NPAD * 256 * sizeof(ushort);  // 51.2MB
    ushort* obf  = (ushort*)w; w += (size_t)NPAD * 256 * sizeof(ushort);  // 51.2MB
    ushort* W1t  = (ushort*)w; w += (size_t)256 * 128 * sizeof(ushort);
    ushort* W2t  = (ushort*)w; w += (size_t)256 * 256 * sizeof(ushort);
    float2* Wf   = (float2*)w; w += 256 * sizeof(float2);
    float*  bfv  = (float*)w;  w += 4 * sizeof(float);
    float2* as_  = (float2*)w; w += (size_t)NPAD * sizeof(float2);
    float2* ad_  = (float2*)w; w += (size_t)NPAD * sizeof(float2);
    int* deg       = (int*)w; w += (size_t)NNODES * sizeof(int);
    int* row_start = (int*)w; w += (size_t)(NNODES + 16) * sizeof(int);
    int* cursor    = (int*)w; w += (size_t)NNODES * sizeof(int);
    int* csr_src   = (int*)w; w += (size_t)ETOT * sizeof(int);
    int* bsum      = (int*)w; w += 512 * sizeof(int);
    int* bsum2     = (int*)w; w += 512 * sizeof(int);

    const int SCAN_BLOCKS = (NNODES + 255) / 256;   // 391
    const int NODE_WAVES  = (NNODES + 3) / 4;       // 25000
    const int MB = NPAD / 64;                       // 1563

    // --- CSR build ---
    hipMemsetAsync(deg, 0, (size_t)NNODES * sizeof(int), stream);
    hist_kernel<<<(ETOT + 255) / 256, 256, 0, stream>>>(ei, deg);
    scan1_kernel<<<SCAN_BLOCKS, 256, 0, stream>>>(deg, row_start, bsum);
    scan2_kernel<<<1, 512, 0, stream>>>(bsum, bsum2, SCAN_BLOCKS);
    scan3_kernel<<<SCAN_BLOCKS, 256, 0, stream>>>(row_start, bsum2, cursor);
    scatter_kernel<<<(ETOT + 255) / 256, 256, 0, stream>>>(ei, cursor, csr_src);

    // --- weight prep ---
    transpose_bf_kernel<<<(128 * 256 + 255) / 256, 256, 0, stream>>>(W1, W1t, 128, 256);
    transpose_bf_kernel<<<(256 * 256 + 255) / 256, 256, 0, stream>>>(W2, W2t, 256, 256);
    fw_kernel<<<1, 256, 0, stream>>>(Wp1, bp1, Wp2, bp2, Wf, bfv);

    // --- layer 1 ---
    mfma_gemm_f32A<<<dim3(MB, 2), 256, 0, stream>>>(x, W1t, hbf, (float*)as_, (float*)ad_,
                                                    a_src1, a_dst1, 128);
    gather_kernel<<<NODE_WAVES, 256, 0, stream>>>((const uint2*)hbf, row_start, csr_src,
                                                  as_, ad_, (const float4*)b1, (uint2*)obf,
                                                  (const float4*)Wf, bfv, (float2*)outp, 0);

    // --- layer 2 (gather fused with post_mp) ---
    mfma_gemm_bf16A<<<dim3(MB, 2), 256, 0, stream>>>(obf, W2t, hbf, (float*)as_, (float*)ad_,
                                                     a_src2, a_dst2, 256);
    gather_kernel<<<NODE_WAVES, 256, 0, stream>>>((const uint2*)hbf, row_start, csr_src,
                                                  as_, ad_, (const float4*)b2, (uint2*)obf,
                                                  (const float4*)Wf, bfv, (float2*)outp, 1);
}

// Round 6
// 436.609 us; speedup vs baseline: 2.7765x; 1.0276x over previous
//
#include <hip/hip_runtime.h>
#include <hip/hip_bf16.h>
#include <math.h>

// Problem constants (match reference)
#define NNODES 100000
#define NPAD   100032        // padded to multiple of 64 for guard-free GEMM
#define IN_DIM 128
#define HID 128
#define HEADS 2
#define F2 256               // HEADS*HID
#define NEDGES 800000
#define ETOT 900000          // NEDGES + NNODES self-loops
#define NEG_SLOPE 0.2f

typedef unsigned int uint;
typedef unsigned short ushort;
typedef __attribute__((ext_vector_type(8))) short short8;
typedef __attribute__((ext_vector_type(4))) float floatx4;

__device__ __forceinline__ ushort f2bf(float f) {
    uint u = __builtin_bit_cast(uint, f);
    u += 0x7fffu + ((u >> 16) & 1u);       // round-to-nearest-even
    return (ushort)(u >> 16);
}
__device__ __forceinline__ float bf2f(uint u16) {
    return __builtin_bit_cast(float, u16 << 16);
}
__device__ __forceinline__ float wred_sum(float v) {
    for (int o = 32; o; o >>= 1) v += __shfl_xor(v, o);
    return v;
}

// ---------------------------------------------------------------------------
// CSR build: histogram -> per-block scan -> fixup(+block-sum scan) -> scatter
// ---------------------------------------------------------------------------
__global__ __launch_bounds__(256) void hist_kernel(const int* __restrict__ ei,
                                                   int* __restrict__ deg) {
    int i = blockIdx.x * 256 + threadIdx.x;
    if (i >= ETOT) return;
    int dst = (i < NEDGES) ? ei[NEDGES + i] : (i - NEDGES);
    atomicAdd(&deg[dst], 1);
}

__global__ __launch_bounds__(256) void scan1_kernel(const int* __restrict__ deg,
                                                    int* __restrict__ row_start,
                                                    int* __restrict__ bsum) {
    __shared__ int s[256];
    int t = threadIdx.x;
    int i = blockIdx.x * 256 + t;
    int v = (i < NNODES) ? deg[i] : 0;
    s[t] = v;
    __syncthreads();
    for (int off = 1; off < 256; off <<= 1) {
        int x = (t >= off) ? s[t - off] : 0;
        __syncthreads();
        s[t] += x;
        __syncthreads();
    }
    if (i < NNODES) row_start[i] = s[t] - v;   // exclusive within block
    if (t == 255) bsum[blockIdx.x] = s[255];
}

// adds prefix of bsum (computed in-kernel) + writes cursor
__global__ __launch_bounds__(256) void scan_fix_kernel(int* __restrict__ row_start,
                                                       const int* __restrict__ bsum,
                                                       int* __restrict__ cursor) {
    __shared__ int sh[256];
    int t = threadIdx.x, bid = blockIdx.x;
    int v = 0;
    for (int k = t; k < bid; k += 256) v += bsum[k];
    sh[t] = v;
    __syncthreads();
    for (int off = 128; off; off >>= 1) {
        if (t < off) sh[t] += sh[t + off];
        __syncthreads();
    }
    int boff = sh[0];
    int i = bid * 256 + t;
    if (i == 0) row_start[NNODES] = ETOT;
    if (i < NNODES) {
        int r = row_start[i] + boff;
        row_start[i] = r;
        cursor[i] = r;
    }
}

__global__ __launch_bounds__(256) void scatter_kernel(const int* __restrict__ ei,
                                                      int* __restrict__ cursor,
                                                      int* __restrict__ csr_src) {
    int i = blockIdx.x * 256 + threadIdx.x;
    if (i >= ETOT) return;
    int src, dst;
    if (i < NEDGES) { src = ei[i]; dst = ei[NEDGES + i]; }
    else            { src = i - NEDGES; dst = src; }
    int pos = atomicAdd(&cursor[dst], 1);
    csr_src[pos] = src;
}

// ---------------------------------------------------------------------------
// merged weight prep: W1^T, W2^T (bf16) + fused post_mp weights
// grid = 385 blocks: [0,128) W1t, [128,384) W2t, 384 fw
// ---------------------------------------------------------------------------
__global__ __launch_bounds__(256) void prep_kernel(const float* __restrict__ W1,
                                                   ushort* __restrict__ W1t,
                                                   const float* __restrict__ W2,
                                                   ushort* __restrict__ W2t,
                                                   const float* __restrict__ Wp1,
                                                   const float* __restrict__ bp1,
                                                   const float* __restrict__ Wp2,
                                                   const float* __restrict__ bp2,
                                                   float2* __restrict__ Wf,
                                                   float* __restrict__ bfv) {
    int b = blockIdx.x, t = threadIdx.x;
    if (b < 128) {                       // W1t[n][k] = W1[k][n], K=128, N=256
        int i = b * 256 + t;
        int n = i >> 7, k = i & 127;
        W1t[n * 128 + k] = f2bf(W1[k * 256 + n]);
    } else if (b < 384) {                // W2t[n][k] = W2[k][n], K=256, N=256
        int i = (b - 128) * 256 + t;
        int n = i >> 8, k = i & 255;
        W2t[n * 256 + k] = f2bf(W2[k * 256 + n]);
    } else {                             // Wf[k] = Wp1[k][:] @ Wp2 ; bfv
        float s0 = 0.f, s1 = 0.f;
        for (int m = 0; m < 128; m++) {
            float w = Wp1[t * 128 + m];
            s0 += w * Wp2[2 * m];
            s1 += w * Wp2[2 * m + 1];
        }
        Wf[t] = make_float2(s0, s1);
        if (t < 2) {
            float bb = bp2[t];
            for (int m = 0; m < 128; m++) bb += bp1[m] * Wp2[2 * m + t];
            bfv[t] = bb;
        }
    }
}

// ---------------------------------------------------------------------------
// bf16 MFMA GEMM, block tile 64 rows x 128 cols (one full head per block y).
// 4 waves: wave w = rows w*16..w*16+15, all 128 cols (8 MFMA per BK=32).
// Fused alpha logits written NON-atomically (block covers the whole head).
// ---------------------------------------------------------------------------
__global__ __launch_bounds__(256) void mfma_gemm_f32A(const float* __restrict__ A,
                                                      const ushort* __restrict__ Bt,
                                                      ushort* __restrict__ C,
                                                      float* __restrict__ as_f,
                                                      float* __restrict__ ad_f,
                                                      const float* __restrict__ aS,
                                                      const float* __restrict__ aD,
                                                      int K) {
    __shared__ ushort As[64][40];
    __shared__ ushort Bs[128][40];
    int t = threadIdx.x;
    int wave = t >> 6, lane = t & 63;
    int quad = lane >> 4, l16 = lane & 15;
    size_t rowBase = (size_t)blockIdx.x * 64;
    int colBase = blockIdx.y * 128;
    int head = blockIdx.y;

    floatx4 acc[8];
#pragma unroll
    for (int i = 0; i < 8; i++) acc[i] = (floatx4){0.f, 0.f, 0.f, 0.f};

    int ar = t >> 2, ac = (t & 3) * 8;
    int agr = (int)rowBase + ar;
    const float*  Ap  = A + (size_t)agr * K + ac;
    const ushort* Bp0 = Bt + (size_t)(colBase + ar) * K + ac;
    const ushort* Bp1 = Bp0 + (size_t)64 * K;
    bool aok = agr < NNODES;

    for (int k0 = 0; k0 < K; k0 += 32) {
        float4 f0 = make_float4(0.f, 0.f, 0.f, 0.f), f1 = f0;
        if (aok) {
            f0 = *reinterpret_cast<const float4*>(Ap + k0);
            f1 = *reinterpret_cast<const float4*>(Ap + k0 + 4);
        }
        uint4 b0 = *reinterpret_cast<const uint4*>(Bp0 + k0);
        uint4 b1 = *reinterpret_cast<const uint4*>(Bp1 + k0);
        uint4 av;
        av.x = (uint)f2bf(f0.x) | ((uint)f2bf(f0.y) << 16);
        av.y = (uint)f2bf(f0.z) | ((uint)f2bf(f0.w) << 16);
        av.z = (uint)f2bf(f1.x) | ((uint)f2bf(f1.y) << 16);
        av.w = (uint)f2bf(f1.z) | ((uint)f2bf(f1.w) << 16);
        *reinterpret_cast<uint4*>(&As[ar][ac])      = av;
        *reinterpret_cast<uint4*>(&Bs[ar][ac])      = b0;
        *reinterpret_cast<uint4*>(&Bs[64 + ar][ac]) = b1;
        __syncthreads();

        union { uint4 u; short8 s; } afr, bfr;
        afr.u = *reinterpret_cast<const uint4*>(&As[wave * 16 + l16][quad * 8]);
#pragma unroll
        for (int nt = 0; nt < 8; nt++) {
            bfr.u = *reinterpret_cast<const uint4*>(&Bs[nt * 16 + l16][quad * 8]);
            acc[nt] = __builtin_amdgcn_mfma_f32_16x16x32_bf16(afr.s, bfr.s, acc[nt], 0, 0, 0);
        }
        __syncthreads();
    }

    // C write: D row = quad*4+reg, col = l16 within 16x16 tile
#pragma unroll
    for (int nt = 0; nt < 8; nt++) {
        int col = colBase + nt * 16 + l16;
#pragma unroll
        for (int r = 0; r < 4; r++) {
            size_t row = rowBase + wave * 16 + quad * 4 + r;
            C[row * F2 + col] = f2bf(acc[nt][r]);
        }
    }
    // fused alpha logits over the full head (non-atomic)
    float aSv[8], aDv[8];
#pragma unroll
    for (int nt = 0; nt < 8; nt++) {
        int c = colBase + nt * 16 + l16;
        aSv[nt] = aS[c];
        aDv[nt] = aD[c];
    }
#pragma unroll
    for (int r = 0; r < 4; r++) {
        float ps = 0.f, pd = 0.f;
#pragma unroll
        for (int nt = 0; nt < 8; nt++) {
            ps += acc[nt][r] * aSv[nt];
            pd += acc[nt][r] * aDv[nt];
        }
#pragma unroll
        for (int o = 1; o < 16; o <<= 1) {
            ps += __shfl_xor(ps, o);
            pd += __shfl_xor(pd, o);
        }
        if (l16 == 0) {
            size_t row = rowBase + wave * 16 + quad * 4 + r;
            as_f[2 * row + head] = ps;
            ad_f[2 * row + head] = pd;
        }
    }
}

// same but A already bf16 (padded, no guard)
__global__ __launch_bounds__(256) void mfma_gemm_bf16A(const ushort* __restrict__ A,
                                                       const ushort* __restrict__ Bt,
                                                       ushort* __restrict__ C,
                                                       float* __restrict__ as_f,
                                                       float* __restrict__ ad_f,
                                                       const float* __restrict__ aS,
                                                       const float* __restrict__ aD,
                                                       int K) {
    __shared__ ushort As[64][40];
    __shared__ ushort Bs[128][40];
    int t = threadIdx.x;
    int wave = t >> 6, lane = t & 63;
    int quad = lane >> 4, l16 = lane & 15;
    size_t rowBase = (size_t)blockIdx.x * 64;
    int colBase = blockIdx.y * 128;
    int head = blockIdx.y;

    floatx4 acc[8];
#pragma unroll
    for (int i = 0; i < 8; i++) acc[i] = (floatx4){0.f, 0.f, 0.f, 0.f};

    int ar = t >> 2, ac = (t & 3) * 8;
    const ushort* Ap  = A + (rowBase + ar) * K + ac;
    const ushort* Bp0 = Bt + (size_t)(colBase + ar) * K + ac;
    const ushort* Bp1 = Bp0 + (size_t)64 * K;

    for (int k0 = 0; k0 < K; k0 += 32) {
        uint4 av = *reinterpret_cast<const uint4*>(Ap + k0);
        uint4 b0 = *reinterpret_cast<const uint4*>(Bp0 + k0);
        uint4 b1 = *reinterpret_cast<const uint4*>(Bp1 + k0);
        *reinterpret_cast<uint4*>(&As[ar][ac])      = av;
        *reinterpret_cast<uint4*>(&Bs[ar][ac])      = b0;
        *reinterpret_cast<uint4*>(&Bs[64 + ar][ac]) = b1;
        __syncthreads();

        union { uint4 u; short8 s; } afr, bfr;
        afr.u = *reinterpret_cast<const uint4*>(&As[wave * 16 + l16][quad * 8]);
#pragma unroll
        for (int nt = 0; nt < 8; nt++) {
            bfr.u = *reinterpret_cast<const uint4*>(&Bs[nt * 16 + l16][quad * 8]);
            acc[nt] = __builtin_amdgcn_mfma_f32_16x16x32_bf16(afr.s, bfr.s, acc[nt], 0, 0, 0);
        }
        __syncthreads();
    }

#pragma unroll
    for (int nt = 0; nt < 8; nt++) {
        int col = colBase + nt * 16 + l16;
#pragma unroll
        for (int r = 0; r < 4; r++) {
            size_t row = rowBase + wave * 16 + quad * 4 + r;
            C[row * F2 + col] = f2bf(acc[nt][r]);
        }
    }
    float aSv[8], aDv[8];
#pragma unroll
    for (int nt = 0; nt < 8; nt++) {
        int c = colBase + nt * 16 + l16;
        aSv[nt] = aS[c];
        aDv[nt] = aD[c];
    }
#pragma unroll
    for (int r = 0; r < 4; r++) {
        float ps = 0.f, pd = 0.f;
#pragma unroll
        for (int nt = 0; nt < 8; nt++) {
            ps += acc[nt][r] * aSv[nt];
            pd += acc[nt][r] * aDv[nt];
        }
#pragma unroll
        for (int o = 1; o < 16; o <<= 1) {
            ps += __shfl_xor(ps, o);
            pd += __shfl_xor(pd, o);
        }
        if (l16 == 0) {
            size_t row = rowBase + wave * 16 + quad * 4 + r;
            as_f[2 * row + head] = ps;
            ad_f[2 * row + head] = pd;
        }
    }
}

// ---------------------------------------------------------------------------
// fully-fused segment softmax + weighted gather. Wave per node, no LDS.
// Per-lane weights (selected head only -> one exp per edge per lane).
// 4 independent 512B h-row loads in flight; masked 4-wide tail (clamped
// index duplicates a cache-hot row; weight zeroed) -> no serial remainder.
// final_mode: 0 = write bf16 row (relu), 1 = fuse post_mp GEMV + sigmoid.
// ---------------------------------------------------------------------------
__global__ __launch_bounds__(256) void gather_kernel(const uint2* __restrict__ hb2,
                                                     const int* __restrict__ row_start,
                                                     const int* __restrict__ csr_src,
                                                     const float2* __restrict__ as_,
                                                     const float2* __restrict__ ad_,
                                                     const float4* __restrict__ bias4,
                                                     uint2* __restrict__ outb2,
                                                     const float4* __restrict__ WfA,
                                                     const float* __restrict__ bfv,
                                                     float2* __restrict__ outp,
                                                     int final_mode) {
    int wave = threadIdx.x >> 6, lane = threadIdx.x & 63;
    int n = blockIdx.x * 4 + wave;
    if (n >= NNODES) return;
    int beg = row_start[n], end = row_start[n + 1];
    float2 ad = ad_[n];
    bool head1 = lane >= 32;   // lanes 0-31: head0 feats, 32-63: head1 feats
    float adsel = head1 ? ad.y : ad.x;

    float a0 = 0.f, a1 = 0.f, a2 = 0.f, a3 = 0.f;
    float aden = 0.f;          // full selected-head weight sum (no reduction needed)
    const char* hbase = (const char*)hb2;
    uint laneoff = (uint)lane * 8u;

    int j = beg;
    for (; j + 3 < end; j += 4) {
        int s0 = csr_src[j],     s1 = csr_src[j + 1];
        int s2 = csr_src[j + 2], s3 = csr_src[j + 3];
        float2 q0 = as_[s0], q1 = as_[s1], q2 = as_[s2], q3 = as_[s3];
        uint2 h0 = *(const uint2*)(hbase + (size_t)(((uint)s0 << 9) + laneoff));
        uint2 h1 = *(const uint2*)(hbase + (size_t)(((uint)s1 << 9) + laneoff));
        uint2 h2 = *(const uint2*)(hbase + (size_t)(((uint)s2 << 9) + laneoff));
        uint2 h3 = *(const uint2*)(hbase + (size_t)(((uint)s3 << 9) + laneoff));
        float l0 = (head1 ? q0.y : q0.x) + adsel; l0 = l0 > 0.f ? l0 : NEG_SLOPE * l0;
        float l1 = (head1 ? q1.y : q1.x) + adsel; l1 = l1 > 0.f ? l1 : NEG_SLOPE * l1;
        float l2 = (head1 ? q2.y : q2.x) + adsel; l2 = l2 > 0.f ? l2 : NEG_SLOPE * l2;
        float l3 = (head1 ? q3.y : q3.x) + adsel; l3 = l3 > 0.f ? l3 : NEG_SLOPE * l3;
        float w0 = __expf(l0), w1 = __expf(l1), w2 = __expf(l2), w3 = __expf(l3);
        aden += (w0 + w1) + (w2 + w3);
        a0 += w0 * bf2f(h0.x & 0xffffu) + w1 * bf2f(h1.x & 0xffffu)
            + w2 * bf2f(h2.x & 0xffffu) + w3 * bf2f(h3.x & 0xffffu);
        a1 += w0 * bf2f(h0.x >> 16) + w1 * bf2f(h1.x >> 16)
            + w2 * bf2f(h2.x >> 16) + w3 * bf2f(h3.x >> 16);
        a2 += w0 * bf2f(h0.y & 0xffffu) + w1 * bf2f(h1.y & 0xffffu)
            + w2 * bf2f(h2.y & 0xffffu) + w3 * bf2f(h3.y & 0xffffu);
        a3 += w0 * bf2f(h0.y >> 16) + w1 * bf2f(h1.y >> 16)
            + w2 * bf2f(h2.y >> 16) + w3 * bf2f(h3.y >> 16);
    }
    if (j < end) {             // masked 4-wide tail (clamped idx = hot line)
        int e1 = j + 1 < end ? j + 1 : end - 1;
        int e2 = j + 2 < end ? j + 2 : end - 1;
        int e3 = j + 3 < end ? j + 3 : end - 1;
        int s0 = csr_src[j], s1 = csr_src[e1], s2 = csr_src[e2], s3 = csr_src[e3];
        float2 q0 = as_[s0], q1 = as_[s1], q2 = as_[s2], q3 = as_[s3];
        uint2 h0 = *(const uint2*)(hbase + (size_t)(((uint)s0 << 9) + laneoff));
        uint2 h1 = *(const uint2*)(hbase + (size_t)(((uint)s1 << 9) + laneoff));
        uint2 h2 = *(const uint2*)(hbase + (size_t)(((uint)s2 << 9) + laneoff));
        uint2 h3 = *(const uint2*)(hbase + (size_t)(((uint)s3 << 9) + laneoff));
        float l0 = (head1 ? q0.y : q0.x) + adsel; l0 = l0 > 0.f ? l0 : NEG_SLOPE * l0;
        float l1 = (head1 ? q1.y : q1.x) + adsel; l1 = l1 > 0.f ? l1 : NEG_SLOPE * l1;
        float l2 = (head1 ? q2.y : q2.x) + adsel; l2 = l2 > 0.f ? l2 : NEG_SLOPE * l2;
        float l3 = (head1 ? q3.y : q3.x) + adsel; l3 = l3 > 0.f ? l3 : NEG_SLOPE * l3;
        float w0 = __expf(l0);
        float w1 = (j + 1 < end) ? __expf(l1) : 0.f;
        float w2 = (j + 2 < end) ? __expf(l2) : 0.f;
        float w3 = (j + 3 < end) ? __expf(l3) : 0.f;
        aden += (w0 + w1) + (w2 + w3);
        a0 += w0 * bf2f(h0.x & 0xffffu) + w1 * bf2f(h1.x & 0xffffu)
            + w2 * bf2f(h2.x & 0xffffu) + w3 * bf2f(h3.x & 0xffffu);
        a1 += w0 * bf2f(h0.x >> 16) + w1 * bf2f(h1.x >> 16)
            + w2 * bf2f(h2.x >> 16) + w3 * bf2f(h3.x >> 16);
        a2 += w0 * bf2f(h0.y & 0xffffu) + w1 * bf2f(h1.y & 0xffffu)
            + w2 * bf2f(h2.y & 0xffffu) + w3 * bf2f(h3.y & 0xffffu);
        a3 += w0 * bf2f(h0.y >> 16) + w1 * bf2f(h1.y >> 16)
            + w2 * bf2f(h2.y >> 16) + w3 * bf2f(h3.y >> 16);
    }

    float inv = 1.f / (aden + 1e-16f);
    float4 b = bias4[lane];
    float o0 = fmaxf(a0 * inv + b.x, 0.f);
    float o1 = fmaxf(a1 * inv + b.y, 0.f);
    float o2 = fmaxf(a2 * inv + b.z, 0.f);
    float o3 = fmaxf(a3 * inv + b.w, 0.f);
    if (!final_mode) {
        uint2 pk;
        pk.x = (uint)f2bf(o0) | ((uint)f2bf(o1) << 16);
        pk.y = (uint)f2bf(o2) | ((uint)f2bf(o3) << 16);
        outb2[(size_t)n * 64 + lane] = pk;
    } else {
        float4 wa = WfA[2 * lane];
        float4 wb = WfA[2 * lane + 1];
        float p0 = o0 * wa.x + o1 * wa.z + o2 * wb.x + o3 * wb.z;
        float p1 = o0 * wa.y + o1 * wa.w + o2 * wb.y + o3 * wb.w;
        p0 = wred_sum(p0);
        p1 = wred_sum(p1);
        if (lane == 0) {
            float2 r;
            r.x = 1.f / (1.f + __expf(-(p0 + bfv[0])));
            r.y = 1.f / (1.f + __expf(-(p1 + bfv[1])));
            outp[n] = r;
        }
    }
}

// ---------------------------------------------------------------------------
extern "C" void kernel_launch(void* const* d_in, const int* in_sizes, int n_in,
                              void* d_out, int out_size, void* d_ws, size_t ws_size,
                              hipStream_t stream) {
    const float* x      = (const float*)d_in[0];
    const int*   ei     = (const int*)d_in[1];
    const float* W1     = (const float*)d_in[2];
    const float* a_src1 = (const float*)d_in[3];
    const float* a_dst1 = (const float*)d_in[4];
    const float* b1     = (const float*)d_in[5];
    const float* W2     = (const float*)d_in[6];
    const float* a_src2 = (const float*)d_in[7];
    const float* a_dst2 = (const float*)d_in[8];
    const float* b2     = (const float*)d_in[9];
    const float* Wp1    = (const float*)d_in[10];
    const float* bp1    = (const float*)d_in[11];
    const float* Wp2    = (const float*)d_in[12];
    const float* bp2    = (const float*)d_in[13];
    float* outp = (float*)d_out;

    // workspace carve-up (all regions 16B aligned)
    char* w = (char*)d_ws;
    ushort* hbf  = (ushort*)w; w += (size_t)NPAD * 256 * sizeof(ushort);  // 51.2MB
    ushort* obf  = (ushort*)w; w += (size_t)NPAD * 256 * sizeof(ushort);  // 51.2MB
    ushort* W1t  = (ushort*)w; w += (size_t)256 * 128 * sizeof(ushort);
    ushort* W2t  = (ushort*)w; w += (size_t)256 * 256 * sizeof(ushort);
    float2* Wf   = (float2*)w; w += 256 * sizeof(float2);
    float*  bfv  = (float*)w;  w += 4 * sizeof(float);
    float2* as_  = (float2*)w; w += (size_t)NPAD * sizeof(float2);
    float2* ad_  = (float2*)w; w += (size_t)NPAD * sizeof(float2);
    int* deg       = (int*)w; w += (size_t)NNODES * sizeof(int);
    int* row_start = (int*)w; w += (size_t)(NNODES + 16) * sizeof(int);
    int* cursor    = (int*)w; w += (size_t)NNODES * sizeof(int);
    int* csr_src   = (int*)w; w += (size_t)ETOT * sizeof(int);
    int* bsum      = (int*)w; w += 512 * sizeof(int);

    const int SCAN_BLOCKS = (NNODES + 255) / 256;   // 391
    const int NODE_WAVES  = (NNODES + 3) / 4;       // 25000
    const int MB = NPAD / 64;                       // 1563

    // --- CSR build ---
    hipMemsetAsync(deg, 0, (size_t)NNODES * sizeof(int), stream);
    hist_kernel<<<(ETOT + 255) / 256, 256, 0, stream>>>(ei, deg);
    scan1_kernel<<<SCAN_BLOCKS, 256, 0, stream>>>(deg, row_start, bsum);
    scan_fix_kernel<<<SCAN_BLOCKS, 256, 0, stream>>>(row_start, bsum, cursor);
    scatter_kernel<<<(ETOT + 255) / 256, 256, 0, stream>>>(ei, cursor, csr_src);

    // --- weight prep (merged) ---
    prep_kernel<<<385, 256, 0, stream>>>(W1, W1t, W2, W2t, Wp1, bp1, Wp2, bp2, Wf, bfv);

    // --- layer 1 ---
    mfma_gemm_f32A<<<dim3(MB, 2), 256, 0, stream>>>(x, W1t, hbf, (float*)as_, (float*)ad_,
                                                    a_src1, a_dst1, 128);
    gather_kernel<<<NODE_WAVES, 256, 0, stream>>>((const uint2*)hbf, row_start, csr_src,
                                                  as_, ad_, (const float4*)b1, (uint2*)obf,
                                                  (const float4*)Wf, bfv, (float2*)outp, 0);

    // --- layer 2 (gather fused with post_mp) ---
    mfma_gemm_bf16A<<<dim3(MB, 2), 256, 0, stream>>>(obf, W2t, hbf, (float*)as_, (float*)ad_,
                                                     a_src2, a_dst2, 256);
    gather_kernel<<<NODE_WAVES, 256, 0, stream>>>((const uint2*)hbf, row_start, csr_src,
                                                  as_, ad_, (const float4*)b2, (uint2*)obf,
                                                  (const float4*)Wf, bfv, (float2*)outp, 1);
}